// Round 11
// baseline (3365.150 us; speedup 1.0000x reference)
//
#include <hip/hip_runtime.h>
#include <hip/hip_bf16.h>

typedef unsigned short u16;
typedef unsigned char u8;
typedef unsigned int u32;
typedef __attribute__((ext_vector_type(8))) short bf16x8;
typedef __attribute__((ext_vector_type(4))) float f32x4;
typedef __attribute__((ext_vector_type(4))) unsigned int u32x4;

__device__ __forceinline__ float us2f(u16 u){ return __uint_as_float(((unsigned)u)<<16); }
__device__ __forceinline__ u16 f2us(float f){
  __hip_bfloat16 h = __float2bfloat16(f);
  union { __hip_bfloat16 b; u16 s; } cv; cv.b = h; return cv.s;
}
__device__ __forceinline__ float gelu_f(float v){ return 0.5f*v*(1.f+erff(v*0.70710678118654752f)); }
__device__ __forceinline__ float sigm_f(float v){ return 1.f/(1.f+expf(-v)); }

#define BNSC 0.9999950000374997f  /* 1/sqrt(1+1e-5) */

// ---------------------------------------------------------------- fused prep
struct PrepArgs {
  const float *qkv_w, *out_w, *ff1_w, *ff2_w, *g_wih, *fc1_w, *pf_w, *c2_w, *fc2_w, *fc2_b;
  const float *c1_w, *c1_b, *bn2_g;
  const float *map_vec, *mv_w, *mv_b, *row_e, *col_e, *pos_w, *pos_b;
  const int *tm;
  u16 *qkvw_d, *outw_d, *ff1w_d, *ff2w_d, *wihw_d, *fc1w_d, *pfw_d, *w2k_d, *fc2w_d;
  float *fc2b_d, *w1t_d, *t2_d, *s2_d, *mv_d, *pos_d;
  u8 *ecls_d;
  unsigned *bar;
};
#define SB_QKV 2304
#define SB_O   768
#define SB_WIH 1536
#define SB_FC1 1024
#define SB_PF  1152
#define SB_W2  288
#define SB_FC2 128
#define SB_W1T 72
#define SB_T2  1057
#define SB_MV  128
#define SB_POS 169
#define SB_EC  2113
#define PREP_GRID (1+SB_QKV+3*SB_O+SB_WIH+SB_FC1+SB_PF+SB_W2+SB_FC2+SB_W1T+SB_T2+SB_MV+SB_POS+SB_EC)

__global__ __launch_bounds__(256) void prep_kernel(PrepArgs a){
  int bb = blockIdx.x; const int tid = threadIdx.x;
  if (bb < 1){
    a.bar[tid] = 0u; a.bar[256+tid] = 0u;       // 2KB flag region
    if (tid < 128) a.s2_d[tid] = a.bn2_g[tid]*BNSC;
    return;
  } bb -= 1;
  if (bb < SB_QKV){ int i = bb*256+tid; a.qkvw_d[i] = f2us(a.qkv_w[i]); return; } bb -= SB_QKV;
  if (bb < SB_O){ int i = bb*256+tid; a.outw_d[i] = f2us(a.out_w[i]); return; } bb -= SB_O;
  if (bb < SB_O){ int i = bb*256+tid; a.ff1w_d[i] = f2us(a.ff1_w[i]); return; } bb -= SB_O;
  if (bb < SB_O){ int i = bb*256+tid; a.ff2w_d[i] = f2us(a.ff2_w[i]); return; } bb -= SB_O;
  if (bb < SB_WIH){ int i = bb*256+tid; a.wihw_d[i] = f2us(a.g_wih[i]); return; } bb -= SB_WIH;
  if (bb < SB_FC1){ int i = bb*256+tid; a.fc1w_d[i] = f2us(a.fc1_w[i]); return; } bb -= SB_FC1;
  if (bb < SB_PF){
    int i = bb*256+tid;
    int o = i/1152, kp = i%1152, pos = kp>>7, c = kp&127;
    a.pfw_d[i] = f2us(a.pf_w[o*1152 + c*9 + pos]); return;
  } bb -= SB_PF;
  if (bb < SB_W2){
    int i = bb*256+tid;
    int o = i/576, k = i%576, tap = k>>6, ic = k&63, ty = tap/3, tx = tap%3;
    a.w2k_d[i] = f2us(a.c2_w[((o*64 + ic)*3 + ty)*3 + tx]); return;
  } bb -= SB_W2;
  if (bb < SB_FC2){
    int i = bb*256+tid;
    int o = i>>9, k = i&511;
    a.fc2w_d[i] = (o<32) ? f2us(a.fc2_w[o*512+k]) : (u16)0;
    if (i < 64) a.fc2b_d[i] = (i<32) ? a.fc2_b[i] : 0.f;
    return;
  } bb -= SB_FC2;
  if (bb < SB_W1T){
    int i = bb*256+tid;
    int c = i/576, r = i%576, tap = r>>6, o = r&63;
    a.w1t_d[i] = a.c1_w[(o*33 + c)*9 + tap]; return;
  } bb -= SB_W1T;
  if (bb < SB_T2){
    int i = bb*256+tid; if (i >= 169*25*64) return;
    int blk = i/64, o = i%64;
    int p = blk/25, op = blk%25, oy = op/5, ox = op%5;
    int yp = p/13, xp = p%13;
    float acc = a.c1_b[o];
    for (int dy=0; dy<3; dy++) for (int dx=0; dx<3; dx++){
      int Y = oy+dy-1, X = ox+dx-1;
      if (Y<0||Y>4||X<0||X>4) continue;
      int rr = yp + Y - 4, cc = xp + X - 2;
      bool m = (rr>=0) && (cc>=0) && (cc<13) && !(Y==4 && X>=2);
      if (m) acc += a.c1_w[(o*33 + 32)*9 + dy*3 + dx];
    }
    a.t2_d[((long)p*25 + op)*64 + o] = acc; return;
  } bb -= SB_T2;
  if (bb < SB_MV){
    int i = bb*256+tid;
    int bi = i>>8, o = i&255;
    float acc = a.mv_b[o];
    for (int k=0;k<32;k++) acc += a.map_vec[bi*32+k]*a.mv_w[o*32+k];
    a.mv_d[i] = acc; return;
  } bb -= SB_MV;
  if (bb < SB_POS){
    int i = bb*256+tid;
    int p = i>>8, o = i&255;
    int y = p/13, x = p%13;
    const float* wr = a.pos_w + o*512;
    float acc = a.pos_b[o];
    for (int k=0;k<256;k++) acc += a.row_e[y*256+k]*wr[k];
    for (int k=0;k<256;k++) acc += a.col_e[x*256+k]*wr[256+k];
    a.pos_d[i] = acc; return;
  } bb -= SB_POS;
  {
    int id = bb*256+tid; if (id >= 21632*25) return;
    int n = id/25, q = id%25, Y = q/5, X = q%5;
    int b = n/169, p = n%169, yp = p/13, xp = p%13;
    int rr = yp + X - 4, cc = xp + Y - 2;
    int val = 0;
    if (rr>=0 && cc>=0 && cc<13 && !(X==4 && Y>=2)) val = a.tm[b*169 + rr*13 + cc];
    a.ecls_d[id] = (u8)val;
  }
}

// conv1 gather + BN + gelu
__global__ __launch_bounds__(256) void conv1_kernel(
    const u8* __restrict__ ec, const float* __restrict__ w1t, const float* __restrict__ t2,
    const float* __restrict__ bn1g, const float* __restrict__ bn1b, u16* __restrict__ c1out,
    int nbase){
  __shared__ __align__(16) u16 w1s[32*9*64];
  __shared__ u8 ecs[32*25];
  const int tid = threadIdx.x, nl0 = blockIdx.x*32;
  for (int i=tid; i<32*9*64; i+=256) w1s[i] = f2us(w1t[i]);
  for (int i=tid; i<32*25;   i+=256) ecs[i] = ec[((long)nbase + nl0)*25 + i];
  __syncthreads();
  const int grp = tid>>6, o = tid&63;
  const float s1 = bn1g[o]*BNSC, t1 = bn1b[o];
  for (int it = grp; it < 800; it += 4){
    const int nl = it/25, op = it%25, oy = op/5, ox = op%5;
    const int n = nbase + nl0 + nl, p = n%169;
    float acc = t2[((long)p*25 + op)*64 + o];
    #pragma unroll
    for (int dy=0; dy<3; dy++)
      #pragma unroll
      for (int dx=0; dx<3; dx++){
        int Y = oy+dy-1, X = ox+dx-1;
        if (Y>=0 && Y<5 && X>=0 && X<5){
          int e = ecs[nl*25 + Y*5 + X];
          acc += us2f(w1s[(e*9 + dy*3+dx)*64 + o]);
        }
      }
    c1out[((long)(nl0+nl)*25 + op)*64 + o] = f2us(gelu_f(acc*s1 + t1));
  }
}

// --------------------------- BM=64 GEMM (M not divisible by 128: patch_fc)
template<int NT>
__global__ __launch_bounds__(256) void gemm_bt(
    const u16* A, long lda, const u16* __restrict__ W,
    const float* __restrict__ bias,
    u16* outB, long ldc, int N, int K){
  __shared__ __align__(16) u16 As[64][72];
  __shared__ __align__(16) u16 Ws[NT][64][72];
  const int tid = threadIdx.x, wv = tid>>6, lane = tid&63;
  const int quad = lane>>4, l16 = lane&15;
  const int bm = blockIdx.y, bn = blockIdx.x;
  f32x4 acc[NT*4];
  #pragma unroll
  for (int i=0;i<NT*4;i++) acc[i] = (f32x4){0.f,0.f,0.f,0.f};
  const int sm = tid>>2, sk = (tid&3)<<4;
  const long arow = (long)(bm*64 + sm)*lda;
  for (int kb = 0; kb < K; kb += 64){
    int4 a0 = *(const int4*)(A + arow + kb + sk);
    int4 a1 = *(const int4*)(A + arow + kb + sk + 8);
    *(int4*)&As[sm][sk]   = a0;  *(int4*)&As[sm][sk+8] = a1;
    #pragma unroll
    for (int wt=0; wt<NT; wt++){
      const long wrow = (long)(bn*(64*NT) + wt*64 + sm)*K;
      int4 w0 = *(const int4*)(W + wrow + kb + sk);
      int4 w1 = *(const int4*)(W + wrow + kb + sk + 8);
      *(int4*)&Ws[wt][sm][sk]   = w0;  *(int4*)&Ws[wt][sm][sk+8] = w1;
    }
    __syncthreads();
    #pragma unroll
    for (int ks = 0; ks < 64; ks += 32){
      bf16x8 af = *(const bf16x8*)(&As[wv*16 + l16][ks + quad*8]);
      #pragma unroll
      for (int wt=0; wt<NT; wt++)
        #pragma unroll
        for (int s=0; s<4; s++){
          bf16x8 bfv = *(const bf16x8*)(&Ws[wt][s*16 + l16][ks + quad*8]);
          acc[wt*4+s] = __builtin_amdgcn_mfma_f32_16x16x32_bf16(af, bfv, acc[wt*4+s], 0, 0, 0);
        }
    }
    __syncthreads();
  }
  const int mb = bm*64 + wv*16 + quad*4;
  #pragma unroll
  for (int wt=0; wt<NT; wt++)
    #pragma unroll
    for (int s=0; s<4; s++){
      const int n = bn*(64*NT) + wt*64 + s*16 + l16;
      const float bv = bias[n];
      #pragma unroll
      for (int r=0;r<4;r++)
        outB[(long)(mb + r)*ldc + n] = f2us(acc[wt*4+s][r] + bv);
    }
}

// --------------------------- BM=128 GEMM: 2 m-tiles per wave
// OM 0: row-major bf16 out  OM 1: giX scatter  OM 2: LN epilogue  OM 3: head scatter f32
template<int NT, int OM>
__global__ __launch_bounds__(256) void gemm_bt2(
    const u16* A, long lda, const u16* __restrict__ W,
    const float* __restrict__ bias,
    float* outF, u16* outB, long ldc, int N, int K, int act,
    const u16* __restrict__ lbase, const float* __restrict__ lg, const float* __restrict__ lb){
  __shared__ __align__(16) u16 As[128][72];
  __shared__ __align__(16) u16 Ws[NT][64][72];
  const int tid = threadIdx.x, wv = tid>>6, lane = tid&63;
  const int quad = lane>>4, l16 = lane&15;
  const int bm = blockIdx.y, bn = blockIdx.x;
  f32x4 acc[2][NT*4];
  #pragma unroll
  for (int mt=0;mt<2;mt++)
    #pragma unroll
    for (int i=0;i<NT*4;i++) acc[mt][i] = (f32x4){0.f,0.f,0.f,0.f};
  const int smA = tid>>1, skA = (tid&1)<<5;
  const int smW = tid>>2, skW = (tid&3)<<4;
  const long arow = (long)(bm*128 + smA)*lda;
  for (int kb = 0; kb < K; kb += 64){
    int4 a0 = *(const int4*)(A + arow + kb + skA);
    int4 a1 = *(const int4*)(A + arow + kb + skA + 8);
    int4 a2 = *(const int4*)(A + arow + kb + skA + 16);
    int4 a3 = *(const int4*)(A + arow + kb + skA + 24);
    *(int4*)&As[smA][skA]    = a0;  *(int4*)&As[smA][skA+8]  = a1;
    *(int4*)&As[smA][skA+16] = a2;  *(int4*)&As[smA][skA+24] = a3;
    #pragma unroll
    for (int wt=0; wt<NT; wt++){
      const long wrow = (long)(bn*(64*NT) + wt*64 + smW)*K;
      int4 w0 = *(const int4*)(W + wrow + kb + skW);
      int4 w1 = *(const int4*)(W + wrow + kb + skW + 8);
      *(int4*)&Ws[wt][smW][skW]   = w0;  *(int4*)&Ws[wt][smW][skW+8] = w1;
    }
    __syncthreads();
    #pragma unroll
    for (int ks = 0; ks < 64; ks += 32){
      bf16x8 af0 = *(const bf16x8*)(&As[wv*16 + l16][ks + quad*8]);
      bf16x8 af1 = *(const bf16x8*)(&As[64 + wv*16 + l16][ks + quad*8]);
      #pragma unroll
      for (int wt=0; wt<NT; wt++)
        #pragma unroll
        for (int s=0; s<4; s++){
          bf16x8 bfv = *(const bf16x8*)(&Ws[wt][s*16 + l16][ks + quad*8]);
          acc[0][wt*4+s] = __builtin_amdgcn_mfma_f32_16x16x32_bf16(af0, bfv, acc[0][wt*4+s], 0, 0, 0);
          acc[1][wt*4+s] = __builtin_amdgcn_mfma_f32_16x16x32_bf16(af1, bfv, acc[1][wt*4+s], 0, 0, 0);
        }
    }
    __syncthreads();
  }
  if (OM == 2){
    #pragma unroll
    for (int mt=0; mt<2; mt++){
      const int mb = bm*128 + mt*64 + wv*16 + quad*4;
      #pragma unroll
      for (int wt=0; wt<NT; wt++)
        #pragma unroll
        for (int s=0; s<4; s++){
          const int n = wt*64 + s*16 + l16;
          const float bv = bias[n];
          #pragma unroll
          for (int r=0;r<4;r++)
            acc[mt][wt*4+s][r] = acc[mt][wt*4+s][r] + bv + us2f(lbase[(long)(mb+r)*N + n]);
        }
      float mean[4], rstd[4];
      #pragma unroll
      for (int r=0;r<4;r++){
        float s = 0.f;
        #pragma unroll
        for (int i=0;i<NT*4;i++) s += acc[mt][i][r];
        s += __shfl_xor(s,1); s += __shfl_xor(s,2); s += __shfl_xor(s,4); s += __shfl_xor(s,8);
        mean[r] = s / N;
        float v = 0.f;
        #pragma unroll
        for (int i=0;i<NT*4;i++){ float d = acc[mt][i][r]-mean[r]; v += d*d; }
        v += __shfl_xor(v,1); v += __shfl_xor(v,2); v += __shfl_xor(v,4); v += __shfl_xor(v,8);
        rstd[r] = rsqrtf(v/N + 1e-5f);
      }
      #pragma unroll
      for (int wt=0; wt<NT; wt++)
        #pragma unroll
        for (int s=0; s<4; s++){
          const int n = wt*64 + s*16 + l16;
          const float gv = lg[n], bvv = lb[n];
          #pragma unroll
          for (int r=0;r<4;r++)
            outB[(long)(mb+r)*ldc + n] = f2us((acc[mt][wt*4+s][r]-mean[r])*rstd[r]*gv + bvv);
        }
    }
    return;
  }
  #pragma unroll
  for (int mt=0; mt<2; mt++){
    const int mb = bm*128 + mt*64 + wv*16 + quad*4;
    #pragma unroll
    for (int wt=0; wt<NT; wt++)
      #pragma unroll
      for (int s=0; s<4; s++){
        const int n = bn*(64*NT) + wt*64 + s*16 + l16;
        const float bv = bias ? bias[n] : 0.f;
        #pragma unroll
        for (int r=0;r<4;r++){
          float v = acc[mt][wt*4+s][r] + bv;
          if (act==1) v = fmaxf(v, 0.f);
          else if (act==2) v = gelu_f(v);
          if (OM == 1){
            const int m = mb + r, b = m/169, tt = m%169;
            const int gate = n>>9, cblk = (n>>4)&31, jl = n&15;
            outB[(((long)tt*32 + cblk)*3 + gate)*2048 + b*16 + jl] = f2us(v);
          } else if (OM == 3){
            if (n < 32){
              const int m = mb + r, t = m/128, b2 = m%128;
              outF[((long)b2*32 + n)*169 + t] = v;
            }
          } else {
            const long oo = (long)(mb + r)*ldc + n;
            if (outF) outF[oo] = v;
            if (outB) outB[oo] = f2us(v);
          }
        }
      }
  }
}

// conv2 implicit-im2col GEMM
__global__ __launch_bounds__(256) void gemm_conv2(
    const u16* __restrict__ C1, const u16* __restrict__ W,
    const float* __restrict__ bias, const float* __restrict__ scale, const float* __restrict__ shift,
    u16* __restrict__ outB){
  __shared__ __align__(16) u16 As[64][72];
  __shared__ __align__(16) u16 Ws[64][72];
  const int tid = threadIdx.x, wv = tid>>6, lane = tid&63;
  const int quad = lane>>4, l16 = lane&15;
  const int bm = blockIdx.y, bn = blockIdx.x;
  f32x4 acc[4];
  #pragma unroll
  for (int i=0;i<4;i++) acc[i] = (f32x4){0.f,0.f,0.f,0.f};
  const int sm = tid>>2, sk = (tid&3)<<4;
  const int g = bm*64 + sm, n_ = g/9, pos = g%9, py = pos/3, px = pos%3;
  const long wrow = (long)(bn*64 + sm)*576;
  for (int tap = 0; tap < 9; tap++){
    const int kb = tap*64;
    const long aoff = ((long)n_*25 + (py + tap/3)*5 + (px + tap%3))*64 + sk;
    int4 a0 = *(const int4*)(C1 + aoff);
    int4 a1 = *(const int4*)(C1 + aoff + 8);
    int4 w0 = *(const int4*)(W + wrow + kb + sk);
    int4 w1 = *(const int4*)(W + wrow + kb + sk + 8);
    *(int4*)&As[sm][sk]   = a0;  *(int4*)&As[sm][sk+8] = a1;
    *(int4*)&Ws[sm][sk]   = w0;  *(int4*)&Ws[sm][sk+8] = w1;
    __syncthreads();
    #pragma unroll
    for (int ks = 0; ks < 64; ks += 32){
      bf16x8 af = *(const bf16x8*)(&As[wv*16 + l16][ks + quad*8]);
      #pragma unroll
      for (int nt=0; nt<4; nt++){
        bf16x8 bfv = *(const bf16x8*)(&Ws[nt*16 + l16][ks + quad*8]);
        acc[nt] = __builtin_amdgcn_mfma_f32_16x16x32_bf16(af, bfv, acc[nt], 0, 0, 0);
      }
    }
    __syncthreads();
  }
  const int mb = bm*64 + wv*16 + quad*4;
  #pragma unroll
  for (int nt=0; nt<4; nt++){
    const int n = bn*64 + nt*16 + l16;
    const float bv = bias[n], sc = scale[n], sh = shift[n];
    #pragma unroll
    for (int r=0;r<4;r++){
      float v = (acc[nt][r] + bv)*sc + sh;
      outB[(long)(mb + r)*128 + n] = f2us(gelu_f(v));
    }
  }
}

// tokens -> h bf16 [86528][256]; fills slots 0..2
__global__ void token_kernel(const int* __restrict__ tm, const float* __restrict__ te,
                             const float* __restrict__ mv, const float* __restrict__ pos,
                             u16* __restrict__ hB){
  const int n = blockIdx.x, k = threadIdx.x;
  const int b = n/169, p = n%169;
  const int prev = (p==0) ? 31 : tm[b*169 + p - 1];
  const long r0 = (long)n*1024;
  hB[r0 + k]        = f2us(te[prev*256 + k]);
  hB[r0 + 256 + k]  = f2us(mv[b*256 + k]);
  hB[r0 + 512 + k]  = f2us(pos[p*256 + k]);
}

// attention
__global__ __launch_bounds__(256) void attn_kernel(const u16* __restrict__ qkv, u16* o){
  const int n = blockIdx.x*4 + (threadIdx.x>>6);
  const int lane = threadIdx.x & 63;
  float qv[4][2][2], kv[4][2][2], vv[4][2][2];
  #pragma unroll
  for (int tok=0; tok<4; tok++){
    const long rb = (long)(n*4+tok)*768;
    #pragma unroll
    for (int h=0; h<2; h++){
      unsigned u;
      u = *(const unsigned*)(qkv + rb +        h*128 + 2*lane); qv[tok][h][0]=us2f(u&0xffff); qv[tok][h][1]=us2f(u>>16);
      u = *(const unsigned*)(qkv + rb + 256 +  h*128 + 2*lane); kv[tok][h][0]=us2f(u&0xffff); kv[tok][h][1]=us2f(u>>16);
      u = *(const unsigned*)(qkv + rb + 512 +  h*128 + 2*lane); vv[tok][h][0]=us2f(u&0xffff); vv[tok][h][1]=us2f(u>>16);
    }
  }
  float sc[2][4][4];
  #pragma unroll
  for (int h=0; h<2; h++)
    #pragma unroll
    for (int qt=0; qt<4; qt++)
      #pragma unroll
      for (int kt=0; kt<4; kt++){
        float p_ = qv[qt][h][0]*kv[kt][h][0] + qv[qt][h][1]*kv[kt][h][1];
        for (int off=32; off; off>>=1) p_ += __shfl_xor(p_, off);
        sc[h][qt][kt] = p_ * 0.08838834764831845f;
      }
  #pragma unroll
  for (int h=0; h<2; h++)
    #pragma unroll
    for (int qt=0; qt<4; qt++){
      float m = fmaxf(fmaxf(sc[h][qt][0],sc[h][qt][1]),fmaxf(sc[h][qt][2],sc[h][qt][3]));
      float s = 0.f;
      #pragma unroll
      for (int kt=0; kt<4; kt++){ sc[h][qt][kt] = expf(sc[h][qt][kt]-m); s += sc[h][qt][kt]; }
      float inv = 1.f/s;
      #pragma unroll
      for (int kt=0; kt<4; kt++) sc[h][qt][kt] *= inv;
    }
  #pragma unroll
  for (int qt=0; qt<4; qt++)
    #pragma unroll
    for (int h=0; h<2; h++){
      float o0=0.f, o1=0.f;
      #pragma unroll
      for (int kt=0; kt<4; kt++){ o0 += sc[h][qt][kt]*vv[kt][h][0]; o1 += sc[h][qt][kt]*vv[kt][h][1]; }
      unsigned u = (unsigned)f2us(o0) | ((unsigned)f2us(o1)<<16);
      *(unsigned*)(o + (long)(n*4+qt)*256 + h*128 + 2*lane) = u;
    }
}

// LayerNorm — head fcln(+gelu) only
template<int NPL>
__global__ __launch_bounds__(256) void ln_kernel(
    const u16* __restrict__ delta, const u16* __restrict__ base,
    const float* __restrict__ g, const float* __restrict__ b,
    u16* __restrict__ out, int do_gelu){
  const int D = NPL*64;
  const int row = blockIdx.x*4 + (threadIdx.x>>6);
  const int lane = threadIdx.x & 63;
  const long ro = (long)row*D;
  float x[NPL];
  float s = 0.f;
  #pragma unroll
  for (int i=0;i<NPL;i++){
    float v = us2f(delta[ro + i*64 + lane]);
    if (base) v += us2f(base[ro + i*64 + lane]);
    x[i] = v; s += v;
  }
  for (int off=32; off; off>>=1) s += __shfl_xor(s, off);
  const float mean = s / D;
  float var = 0.f;
  #pragma unroll
  for (int i=0;i<NPL;i++){ float dd = x[i]-mean; var += dd*dd; }
  for (int off=32; off; off>>=1) var += __shfl_xor(var, off);
  const float rs = rsqrtf(var/D + 1e-5f);
  #pragma unroll
  for (int i=0;i<NPL;i++){
    float y = (x[i]-mean)*rs*g[i*64+lane] + b[i*64+lane];
    if (do_gelu) y = gelu_f(y);
    out[ro + i*64 + lane] = f2us(y);
  }
}

// GRU v7: R8 structure + distributed per-WG flags (line-disjoint, pipelined poll).
__global__ __launch_bounds__(256) void gru_kernel(
    const u16* __restrict__ gix, const float* __restrict__ whh,
    const float* __restrict__ bhh, u16* __restrict__ hx, u16* __restrict__ hs,
    unsigned* __restrict__ bar){
  __shared__ __align__(16) u16 Wl[48][520];
  __shared__ __align__(16) u16 hbuf[2048];
  const int c = blockIdx.x, tid = threadIdx.x;
  const int wv = tid>>6, lane = tid&63, quad = lane>>4, l16 = lane&15;
  for (int idx = tid; idx < 48*512; idx += 256){
    int g = idx >> 9, k = idx & 511;
    int gate = g >> 4, jl = g & 15;
    Wl[g][k] = f2us(whh[((gate<<9) + (c<<4) + jl)*512 + k]);
  }
  const int j = (c<<4) + l16;
  const float bh_r = bhh[j], bh_z = bhh[512+j], bh_n = bhh[1024+j];
  __syncthreads();
  float hold[2][4] = {{0.f,0.f,0.f,0.f},{0.f,0.f,0.f,0.f}};
  const int jlo = (quad&1)*8, jhiadd = quad>>1;
  for (int t=0; t<169; t++){
    const u16* gbase = gix + ((long)t*32 + c)*3*2048;
    float gr_[2][4], gz_[2][4], gn_[2][4];
    #pragma unroll
    for (int mt=0; mt<2; mt++)
      #pragma unroll
      for (int r=0; r<4; r++){
        const int b = (2*wv+mt)*16 + quad*4 + r;
        gr_[mt][r] = us2f(gbase[       b*16 + l16]);
        gz_[mt][r] = us2f(gbase[2048 + b*16 + l16]);
        gn_[mt][r] = us2f(gbase[4096 + b*16 + l16]);
      }
    if (t>0){
      if (tid < 32){
        const u32* fp = bar + tid*16;       // 64B-spaced flags, 1 lane each, pipelined
        u32 v;
        do {
          asm volatile("global_load_dword %0, %1, off sc0 sc1" : "=v"(v) : "v"(fp));
          asm volatile("s_waitcnt vmcnt(0)" ::: "memory");
        } while ((int)v < t);
      }
      __syncthreads();
    }
    f32x4 acc[2][3];
    #pragma unroll
    for (int mt=0; mt<2; mt++)
      #pragma unroll
      for (int g3=0; g3<3; g3++) acc[mt][g3] = (f32x4){0.f,0.f,0.f,0.f};
    if (t>0){
      const long tb = (long)(t-1)*65536;
      const int b0 = (2*wv+0)*16 + l16, b1 = (2*wv+1)*16 + l16;
      bf16x8 av0[16], av1[16];
      #pragma unroll
      for (int ii=0; ii<16; ii++){
        const long off = tb + (long)(ii*2 + jhiadd)*2048 + jlo;
        const u16* p0 = hx + off + b0*16;
        const u16* p1 = hx + off + b1*16;
        asm volatile("global_load_dwordx4 %0, %1, off sc0 sc1" : "=v"(av0[ii]) : "v"(p0));
        asm volatile("global_load_dwordx4 %0, %1, off sc0 sc1" : "=v"(av1[ii]) : "v"(p1));
      }
      asm volatile("s_waitcnt vmcnt(0)" ::: "memory");
      #pragma unroll
      for (int ii=0; ii<16; ii++){
        asm volatile("" : "+v"(av0[ii]));
        asm volatile("" : "+v"(av1[ii]));
      }
      #pragma unroll
      for (int ii=0; ii<16; ii++){
        const int ks = ii*32;
        #pragma unroll
        for (int g3=0; g3<3; g3++){
          bf16x8 bfv = *(const bf16x8*)(&Wl[g3*16 + l16][ks + quad*8]);
          acc[0][g3] = __builtin_amdgcn_mfma_f32_16x16x32_bf16(av0[ii], bfv, acc[0][g3], 0,0,0);
          acc[1][g3] = __builtin_amdgcn_mfma_f32_16x16x32_bf16(av1[ii], bfv, acc[1][g3], 0,0,0);
        }
      }
    }
    u16 hbv[2][4];
    #pragma unroll
    for (int mt=0; mt<2; mt++)
      #pragma unroll
      for (int r=0; r<4; r++){
        const int b = (2*wv+mt)*16 + quad*4 + r;
        float rr = sigm_f(gr_[mt][r] + acc[mt][0][r] + bh_r);
        float zz = sigm_f(gz_[mt][r] + acc[mt][1][r] + bh_z);
        float nn = tanhf (gn_[mt][r] + rr*(acc[mt][2][r] + bh_n));
        float h = (1.f-zz)*nn + zz*hold[mt][r];
        hold[mt][r] = h;
        hbv[mt][r] = f2us(h);
        hbuf[b*16 + l16] = hbv[mt][r];
      }
    __syncthreads();
    {
      u16* dst = hx + (long)t*65536 + c*2048 + tid*8;
      u32x4 val = *(const u32x4*)((const u32*)hbuf + tid*4);
      asm volatile("global_store_dwordx4 %0, %1, off sc0 sc1" :: "v"(dst), "v"(val) : "memory");
    }
    asm volatile("s_waitcnt vmcnt(0)" ::: "memory");   // this thread's h stores at LLC
    __syncthreads();                                    // => all threads' stores at LLC
    if (tid==0){
      u32 tv = (u32)(t+1);
      const u32* fp = bar + c*16;
      asm volatile("global_store_dword %0, %1, off sc0 sc1" :: "v"(fp), "v"(tv) : "memory");
    }
    // off-critical-path row-major hs for the head GEMM
    #pragma unroll
    for (int mt=0; mt<2; mt++)
      #pragma unroll
      for (int r=0; r<4; r++){
        const int b = (2*wv+mt)*16 + quad*4 + r;
        hs[((long)(t*128 + b))*512 + j] = hbv[mt][r];
      }
  }
}

// ---------------------------------------------------------------- host
extern "C" void kernel_launch(void* const* d_in, const int* in_sizes, int n_in,
                              void* d_out, int out_size, void* d_ws, size_t ws_size,
                              hipStream_t stream){
  (void)in_sizes; (void)n_in; (void)out_size;
  const float* map_vec = (const float*)d_in[0];
  const int*   tm      = (const int*)  d_in[1];
  const float* mv_w  = (const float*)d_in[2];
  const float* mv_b  = (const float*)d_in[3];
  const float* te    = (const float*)d_in[4];
  const float* row_e = (const float*)d_in[5];
  const float* col_e = (const float*)d_in[6];
  const float* pos_w = (const float*)d_in[7];
  const float* pos_b = (const float*)d_in[8];
  const float* c1_w  = (const float*)d_in[9];
  const float* c1_b  = (const float*)d_in[10];
  const float* bn1_g = (const float*)d_in[11];
  const float* bn1_b = (const float*)d_in[12];
  const float* c2_w  = (const float*)d_in[13];
  const float* c2_b  = (const float*)d_in[14];
  const float* bn2_g = (const float*)d_in[15];
  const float* bn2_b = (const float*)d_in[16];
  const float* pf_w  = (const float*)d_in[17];
  const float* pf_b  = (const float*)d_in[18];
  const float* qkv_w = (const float*)d_in[19];
  const float* qkv_b = (const float*)d_in[20];
  const float* out_w = (const float*)d_in[21];
  const float* out_b = (const float*)d_in[22];
  const float* ln1_g = (const float*)d_in[23];
  const float* ln1_b = (const float*)d_in[24];
  const float* ff1_w = (const float*)d_in[25];
  const float* ff1_b = (const float*)d_in[26];
  const float* ff2_w = (const float*)d_in[27];
  const float* ff2_b = (const float*)d_in[28];
  const float* ln2_g = (const float*)d_in[29];
  const float* ln2_b = (const float*)d_in[30];
  const float* g_wih = (const float*)d_in[31];
  const float* g_whh = (const float*)d_in[32];
  const float* g_bih = (const float*)d_in[33];
  const float* g_bhh = (const float*)d_in[34];
  const float* fc1_w = (const float*)d_in[35];
  const float* fc1_b = (const float*)d_in[36];
  const float* fln_g = (const float*)d_in[37];
  const float* fln_b = (const float*)d_in[38];
  const float* fc2_w = (const float*)d_in[39];
  const float* fc2_b = (const float*)d_in[40];

  char* ws = (char*)d_ws;
  constexpr size_t O_BAR  = 0;                         // 2KB: 32 flags @64B
  constexpr size_t O_QKVW = 2048;
  constexpr size_t O_OUTW = O_QKVW + 1179648;
  constexpr size_t O_FF1W = O_OUTW + 393216;
  constexpr size_t O_FF2W = O_FF1W + 393216;
  constexpr size_t O_WIHW = O_FF2W + 393216;
  constexpr size_t O_FC1W = O_WIHW + 786432;
  constexpr size_t O_PFW  = O_FC1W + 524288;
  constexpr size_t O_W2K  = O_PFW  + 589824;
  constexpr size_t O_FC2W = O_W2K  + 147456;
  constexpr size_t O_FC2B = O_FC2W + 65536;
  constexpr size_t O_W1T  = O_FC2B + 256;
  constexpr size_t O_T2   = O_W1T  + 73728;
  constexpr size_t O_S2   = O_T2   + 1081600;
  constexpr size_t O_MV   = O_S2   + 512;
  constexpr size_t O_POS  = O_MV   + 131072;
  constexpr size_t O_ECLS = O_POS  + 173056;
  constexpr size_t O_R0   = ((O_ECLS + 540800 + 255)/256)*256;
  constexpr size_t R0_SZ  = 44302336;
  constexpr size_t O_R1   = O_R0 + R0_SZ;
  constexpr size_t R1_SZ  = 44302336;
  constexpr size_t O_R2   = O_R1 + R1_SZ;
  constexpr size_t R2_SZ  = 33226752;
  constexpr size_t ARENA_END = O_R2 + R2_SZ;
  if (ws_size < ARENA_END) return;
  const size_t O_HB    = O_R0;
  const size_t O_HX    = O_R0;
  const size_t O_HS    = O_R0 + 22151168;
  const size_t O_C1OUT = O_R1;
  const size_t O_OBUF  = O_R1;
  const size_t O_GIX   = O_R1;
  const size_t O_Y1    = O_R1;
  const size_t O_YB    = O_R1 + 22151168;
  const size_t O_C2OUT = O_R2;
  const size_t O_QKVC  = O_R2;

  PrepArgs pa;
  pa.qkv_w=qkv_w; pa.out_w=out_w; pa.ff1_w=ff1_w; pa.ff2_w=ff2_w; pa.g_wih=g_wih;
  pa.fc1_w=fc1_w; pa.pf_w=pf_w; pa.c2_w=c2_w; pa.fc2_w=fc2_w; pa.fc2_b=fc2_b;
  pa.c1_w=c1_w; pa.c1_b=c1_b; pa.bn2_g=bn2_g;
  pa.map_vec=map_vec; pa.mv_w=mv_w; pa.mv_b=mv_b; pa.row_e=row_e; pa.col_e=col_e;
  pa.pos_w=pos_w; pa.pos_b=pos_b; pa.tm=tm;
  pa.qkvw_d=(u16*)(ws+O_QKVW); pa.outw_d=(u16*)(ws+O_OUTW); pa.ff1w_d=(u16*)(ws+O_FF1W);
  pa.ff2w_d=(u16*)(ws+O_FF2W); pa.wihw_d=(u16*)(ws+O_WIHW); pa.fc1w_d=(u16*)(ws+O_FC1W);
  pa.pfw_d=(u16*)(ws+O_PFW); pa.w2k_d=(u16*)(ws+O_W2K); pa.fc2w_d=(u16*)(ws+O_FC2W);
  pa.fc2b_d=(float*)(ws+O_FC2B); pa.w1t_d=(float*)(ws+O_W1T); pa.t2_d=(float*)(ws+O_T2);
  pa.s2_d=(float*)(ws+O_S2); pa.mv_d=(float*)(ws+O_MV); pa.pos_d=(float*)(ws+O_POS);
  pa.ecls_d=(u8*)(ws+O_ECLS); pa.bar=(unsigned*)(ws+O_BAR);
  prep_kernel<<<PREP_GRID, 256, 0, stream>>>(pa);

  token_kernel<<<21632, 256, 0, stream>>>(tm, te, (const float*)(ws+O_MV), (const float*)(ws+O_POS),
      (u16*)(ws+O_HB));

  for (int cc = 0; cc < 2; cc++){
    const int nbase = cc*10816;
    conv1_kernel<<<338, 256, 0, stream>>>((const u8*)(ws+O_ECLS), (const float*)(ws+O_W1T),
        (const float*)(ws+O_T2), bn1_g, bn1_b, (u16*)(ws+O_C1OUT), nbase);
    gemm_conv2<<<dim3(2,1521), 256, 0, stream>>>((const u16*)(ws+O_C1OUT), (const u16*)(ws+O_W2K),
        c2_b, (const float*)(ws+O_S2), bn2_b, (u16*)(ws+O_C2OUT));
    gemm_bt<4><<<dim3(1,169), 256, 0, stream>>>((const u16*)(ws+O_C2OUT), 1152, (const u16*)(ws+O_PFW),
        pf_b, (u16*)(ws+O_HB) + (size_t)nbase*1024 + 768, 1024, 256, 1152);
  }

  for (int l=0; l<3; l++){
    for (int cc = 0; cc < 4; cc++){
      gemm_bt2<4,0><<<dim3(3,169), 256, 0, stream>>>((const u16*)(ws+O_HB) + (size_t)cc*21632*256, 256,
          (const u16*)(ws+O_QKVW) + (size_t)l*768*256, qkv_b + l*768,
          nullptr, (u16*)(ws+O_QKVC), 768, 768, 256, 0, nullptr, nullptr, nullptr);
      attn_kernel<<<1352, 256, 0, stream>>>((const u16*)(ws+O_QKVC),
          (u16*)(ws+O_OBUF) + (size_t)cc*5408*4*256);
    }
    gemm_bt2<4,2><<<dim3(1,676), 256, 0, stream>>>((const u16*)(ws+O_OBUF), 256,
        (const u16*)(ws+O_OUTW) + (size_t)l*256*256, out_b + l*256,
        nullptr, (u16*)(ws+O_HB), 256, 256, 256, 0,
        (const u16*)(ws+O_HB), ln1_g + l*256, ln1_b + l*256);
    gemm_bt2<4,0><<<dim3(1,676), 256, 0, stream>>>((const u16*)(ws+O_HB), 256,
        (const u16*)(ws+O_FF1W) + (size_t)l*256*256, ff1_b + l*256,
        nullptr, (u16*)(ws+O_OBUF), 256, 256, 256, 1, nullptr, nullptr, nullptr);
    gemm_bt2<4,2><<<dim3(1,676), 256, 0, stream>>>((const u16*)(ws+O_OBUF), 256,
        (const u16*)(ws+O_FF2W) + (size_t)l*256*256, ff2_b + l*256,
        nullptr, (u16*)(ws+O_HB), 256, 256, 256, 0,
        (const u16*)(ws+O_HB), ln2_g + l*256, ln2_b + l*256);
  }

  // GRU input projection (M = 21632 sequences -> 169 blocks of 128 rows)
  gemm_bt2<4,1><<<dim3(6,169), 256, 0, stream>>>((const u16*)(ws+O_HB), 1024, (const u16*)(ws+O_WIHW),
      g_bih, nullptr, (u16*)(ws+O_GIX), 1536, 1536, 256, 0, nullptr, nullptr, nullptr);
  gru_kernel<<<32, 256, 0, stream>>>((const u16*)(ws+O_GIX), g_whh, g_bhh,
      (u16*)(ws+O_HX), (u16*)(ws+O_HS), (unsigned*)(ws+O_BAR));

  gemm_bt2<4,0><<<dim3(2,169), 256, 0, stream>>>((const u16*)(ws+O_HS), 512, (const u16*)(ws+O_FC1W),
      fc1_b, nullptr, (u16*)(ws+O_Y1), 512, 512, 512, 0, nullptr, nullptr, nullptr);
  ln_kernel<8><<<5408, 256, 0, stream>>>((const u16*)(ws+O_Y1), nullptr, fln_g, fln_b,
      (u16*)(ws+O_YB), 1);
  gemm_bt2<1,3><<<dim3(1,169), 256, 0, stream>>>((const u16*)(ws+O_YB), 512, (const u16*)(ws+O_FC2W),
      (const float*)(ws+O_FC2B), (float*)d_out, nullptr, 64, 64, 512, 0, nullptr, nullptr, nullptr);
}

// Round 12
// 2909.961 us; speedup vs baseline: 1.1564x; 1.1564x over previous
//
#include <hip/hip_runtime.h>
#include <hip/hip_bf16.h>

typedef unsigned short u16;
typedef unsigned char u8;
typedef unsigned int u32;
typedef __attribute__((ext_vector_type(8))) short bf16x8;
typedef __attribute__((ext_vector_type(4))) float f32x4;
typedef __attribute__((ext_vector_type(4))) unsigned int u32x4;

__device__ __forceinline__ float us2f(u16 u){ return __uint_as_float(((unsigned)u)<<16); }
__device__ __forceinline__ u16 f2us(float f){
  __hip_bfloat16 h = __float2bfloat16(f);
  union { __hip_bfloat16 b; u16 s; } cv; cv.b = h; return cv.s;
}
__device__ __forceinline__ float gelu_f(float v){ return 0.5f*v*(1.f+erff(v*0.70710678118654752f)); }
__device__ __forceinline__ float sigm_f(float v){ return 1.f/(1.f+expf(-v)); }

#define BNSC 0.9999950000374997f  /* 1/sqrt(1+1e-5) */

// ---------------------------------------------------------------- fused prep
struct PrepArgs {
  const float *qkv_w, *out_w, *ff1_w, *ff2_w, *g_wih, *fc1_w, *pf_w, *c2_w, *fc2_w, *fc2_b;
  const float *c1_w, *c1_b, *bn2_g;
  const float *map_vec, *mv_w, *mv_b, *row_e, *col_e, *pos_w, *pos_b;
  const int *tm;
  u16 *qkvw_d, *outw_d, *ff1w_d, *ff2w_d, *wihw_d, *fc1w_d, *pfw_d, *w2k_d, *fc2w_d;
  float *fc2b_d, *w1t_d, *t2_d, *s2_d, *mv_d, *pos_d;
  u8 *ecls_d;
  unsigned *bar;
};
#define SB_QKV 2304
#define SB_O   768
#define SB_WIH 1536
#define SB_FC1 1024
#define SB_PF  1152
#define SB_W2  288
#define SB_FC2 128
#define SB_W1T 72
#define SB_T2  1057
#define SB_MV  128
#define SB_POS 169
#define SB_EC  2113
#define PREP_GRID (1+SB_QKV+3*SB_O+SB_WIH+SB_FC1+SB_PF+SB_W2+SB_FC2+SB_W1T+SB_T2+SB_MV+SB_POS+SB_EC)

__global__ __launch_bounds__(256) void prep_kernel(PrepArgs a){
  int bb = blockIdx.x; const int tid = threadIdx.x;
  if (bb < 1){
    a.bar[tid] = 0u; a.bar[256+tid] = 0u;       // 2KB flag region
    if (tid < 128) a.s2_d[tid] = a.bn2_g[tid]*BNSC;
    return;
  } bb -= 1;
  if (bb < SB_QKV){ int i = bb*256+tid; a.qkvw_d[i] = f2us(a.qkv_w[i]); return; } bb -= SB_QKV;
  if (bb < SB_O){ int i = bb*256+tid; a.outw_d[i] = f2us(a.out_w[i]); return; } bb -= SB_O;
  if (bb < SB_O){ int i = bb*256+tid; a.ff1w_d[i] = f2us(a.ff1_w[i]); return; } bb -= SB_O;
  if (bb < SB_O){ int i = bb*256+tid; a.ff2w_d[i] = f2us(a.ff2_w[i]); return; } bb -= SB_O;
  if (bb < SB_WIH){ int i = bb*256+tid; a.wihw_d[i] = f2us(a.g_wih[i]); return; } bb -= SB_WIH;
  if (bb < SB_FC1){ int i = bb*256+tid; a.fc1w_d[i] = f2us(a.fc1_w[i]); return; } bb -= SB_FC1;
  if (bb < SB_PF){
    int i = bb*256+tid;
    int o = i/1152, kp = i%1152, pos = kp>>7, c = kp&127;
    a.pfw_d[i] = f2us(a.pf_w[o*1152 + c*9 + pos]); return;
  } bb -= SB_PF;
  if (bb < SB_W2){
    int i = bb*256+tid;
    int o = i/576, k = i%576, tap = k>>6, ic = k&63, ty = tap/3, tx = tap%3;
    a.w2k_d[i] = f2us(a.c2_w[((o*64 + ic)*3 + ty)*3 + tx]); return;
  } bb -= SB_W2;
  if (bb < SB_FC2){
    int i = bb*256+tid;
    int o = i>>9, k = i&511;
    a.fc2w_d[i] = (o<32) ? f2us(a.fc2_w[o*512+k]) : (u16)0;
    if (i < 64) a.fc2b_d[i] = (i<32) ? a.fc2_b[i] : 0.f;
    return;
  } bb -= SB_FC2;
  if (bb < SB_W1T){
    int i = bb*256+tid;
    int c = i/576, r = i%576, tap = r>>6, o = r&63;
    a.w1t_d[i] = a.c1_w[(o*33 + c)*9 + tap]; return;
  } bb -= SB_W1T;
  if (bb < SB_T2){
    int i = bb*256+tid; if (i >= 169*25*64) return;
    int blk = i/64, o = i%64;
    int p = blk/25, op = blk%25, oy = op/5, ox = op%5;
    int yp = p/13, xp = p%13;
    float acc = a.c1_b[o];
    for (int dy=0; dy<3; dy++) for (int dx=0; dx<3; dx++){
      int Y = oy+dy-1, X = ox+dx-1;
      if (Y<0||Y>4||X<0||X>4) continue;
      int rr = yp + Y - 4, cc = xp + X - 2;
      bool m = (rr>=0) && (cc>=0) && (cc<13) && !(Y==4 && X>=2);
      if (m) acc += a.c1_w[(o*33 + 32)*9 + dy*3 + dx];
    }
    a.t2_d[((long)p*25 + op)*64 + o] = acc; return;
  } bb -= SB_T2;
  if (bb < SB_MV){
    int i = bb*256+tid;
    int bi = i>>8, o = i&255;
    float acc = a.mv_b[o];
    for (int k=0;k<32;k++) acc += a.map_vec[bi*32+k]*a.mv_w[o*32+k];
    a.mv_d[i] = acc; return;
  } bb -= SB_MV;
  if (bb < SB_POS){
    int i = bb*256+tid;
    int p = i>>8, o = i&255;
    int y = p/13, x = p%13;
    const float* wr = a.pos_w + o*512;
    float acc = a.pos_b[o];
    for (int k=0;k<256;k++) acc += a.row_e[y*256+k]*wr[k];
    for (int k=0;k<256;k++) acc += a.col_e[x*256+k]*wr[256+k];
    a.pos_d[i] = acc; return;
  } bb -= SB_POS;
  {
    int id = bb*256+tid; if (id >= 21632*25) return;
    int n = id/25, q = id%25, Y = q/5, X = q%5;
    int b = n/169, p = n%169, yp = p/13, xp = p%13;
    int rr = yp + X - 4, cc = xp + Y - 2;
    int val = 0;
    if (rr>=0 && cc>=0 && cc<13 && !(X==4 && Y>=2)) val = a.tm[b*169 + rr*13 + cc];
    a.ecls_d[id] = (u8)val;
  }
}

// conv1 gather + BN + gelu
__global__ __launch_bounds__(256) void conv1_kernel(
    const u8* __restrict__ ec, const float* __restrict__ w1t, const float* __restrict__ t2,
    const float* __restrict__ bn1g, const float* __restrict__ bn1b, u16* __restrict__ c1out,
    int nbase){
  __shared__ __align__(16) u16 w1s[32*9*64];
  __shared__ u8 ecs[32*25];
  const int tid = threadIdx.x, nl0 = blockIdx.x*32;
  for (int i=tid; i<32*9*64; i+=256) w1s[i] = f2us(w1t[i]);
  for (int i=tid; i<32*25;   i+=256) ecs[i] = ec[((long)nbase + nl0)*25 + i];
  __syncthreads();
  const int grp = tid>>6, o = tid&63;
  const float s1 = bn1g[o]*BNSC, t1 = bn1b[o];
  for (int it = grp; it < 800; it += 4){
    const int nl = it/25, op = it%25, oy = op/5, ox = op%5;
    const int n = nbase + nl0 + nl, p = n%169;
    float acc = t2[((long)p*25 + op)*64 + o];
    #pragma unroll
    for (int dy=0; dy<3; dy++)
      #pragma unroll
      for (int dx=0; dx<3; dx++){
        int Y = oy+dy-1, X = ox+dx-1;
        if (Y>=0 && Y<5 && X>=0 && X<5){
          int e = ecs[nl*25 + Y*5 + X];
          acc += us2f(w1s[(e*9 + dy*3+dx)*64 + o]);
        }
      }
    c1out[((long)(nl0+nl)*25 + op)*64 + o] = f2us(gelu_f(acc*s1 + t1));
  }
}

// ----------------------------------------------- BM=64 GEMM C = A@W^T (R9-proven)
// OM 0: row-major out (in-place safe when grid.x==1)
// OM 1: giX scatter [t][cblk][gate][b][16], m=b*169+t
// OM 2: LN epilogue (grid.x==1, N==64*NT): outB = LN(acc+bias+lbase)*lg+lb
// OM 3: head scatter: m=t*128+b2, n<32 -> outF[(b2*32+n)*169+t]
template<int NT, int OM>
__global__ __launch_bounds__(256) void gemm_bt(
    const u16* A, long lda, const u16* __restrict__ W,
    const float* __restrict__ bias,
    float* outF, u16* outB, long ldc, int N, int K, int act,
    const u16* __restrict__ lbase, const float* __restrict__ lg, const float* __restrict__ lb){
  __shared__ __align__(16) u16 As[64][72];
  __shared__ __align__(16) u16 Ws[NT][64][72];
  const int tid = threadIdx.x, wv = tid>>6, lane = tid&63;
  const int quad = lane>>4, l16 = lane&15;
  const int bm = blockIdx.y, bn = blockIdx.x;
  f32x4 acc[NT*4];
  #pragma unroll
  for (int i=0;i<NT*4;i++) acc[i] = (f32x4){0.f,0.f,0.f,0.f};
  const int sm = tid>>2, sk = (tid&3)<<4;
  const long arow = (long)(bm*64 + sm)*lda;
  for (int kb = 0; kb < K; kb += 64){
    int4 a0 = *(const int4*)(A + arow + kb + sk);
    int4 a1 = *(const int4*)(A + arow + kb + sk + 8);
    *(int4*)&As[sm][sk]   = a0;  *(int4*)&As[sm][sk+8] = a1;
    #pragma unroll
    for (int wt=0; wt<NT; wt++){
      const long wrow = (long)(bn*(64*NT) + wt*64 + sm)*K;
      int4 w0 = *(const int4*)(W + wrow + kb + sk);
      int4 w1 = *(const int4*)(W + wrow + kb + sk + 8);
      *(int4*)&Ws[wt][sm][sk]   = w0;  *(int4*)&Ws[wt][sm][sk+8] = w1;
    }
    __syncthreads();
    #pragma unroll
    for (int ks = 0; ks < 64; ks += 32){
      bf16x8 af = *(const bf16x8*)(&As[wv*16 + l16][ks + quad*8]);
      #pragma unroll
      for (int wt=0; wt<NT; wt++)
        #pragma unroll
        for (int s=0; s<4; s++){
          bf16x8 bfv = *(const bf16x8*)(&Ws[wt][s*16 + l16][ks + quad*8]);
          acc[wt*4+s] = __builtin_amdgcn_mfma_f32_16x16x32_bf16(af, bfv, acc[wt*4+s], 0, 0, 0);
        }
    }
    __syncthreads();
  }
  const int mb = bm*64 + wv*16 + quad*4;
  if (OM == 2){
    #pragma unroll
    for (int wt=0; wt<NT; wt++)
      #pragma unroll
      for (int s=0; s<4; s++){
        const int n = wt*64 + s*16 + l16;
        const float bv = bias[n];
        #pragma unroll
        for (int r=0;r<4;r++)
          acc[wt*4+s][r] = acc[wt*4+s][r] + bv + us2f(lbase[(long)(mb+r)*N + n]);
      }
    float mean[4], rstd[4];
    #pragma unroll
    for (int r=0;r<4;r++){
      float s = 0.f;
      #pragma unroll
      for (int i=0;i<NT*4;i++) s += acc[i][r];
      s += __shfl_xor(s,1); s += __shfl_xor(s,2); s += __shfl_xor(s,4); s += __shfl_xor(s,8);
      mean[r] = s / N;
      float v = 0.f;
      #pragma unroll
      for (int i=0;i<NT*4;i++){ float d = acc[i][r]-mean[r]; v += d*d; }
      v += __shfl_xor(v,1); v += __shfl_xor(v,2); v += __shfl_xor(v,4); v += __shfl_xor(v,8);
      rstd[r] = rsqrtf(v/N + 1e-5f);
    }
    #pragma unroll
    for (int wt=0; wt<NT; wt++)
      #pragma unroll
      for (int s=0; s<4; s++){
        const int n = wt*64 + s*16 + l16;
        const float gv = lg[n], bvv = lb[n];
        #pragma unroll
        for (int r=0;r<4;r++)
          outB[(long)(mb+r)*ldc + n] = f2us((acc[wt*4+s][r]-mean[r])*rstd[r]*gv + bvv);
      }
    return;
  }
  #pragma unroll
  for (int wt=0; wt<NT; wt++)
    #pragma unroll
    for (int s=0; s<4; s++){
      const int n = bn*(64*NT) + wt*64 + s*16 + l16;
      const float bv = bias ? bias[n] : 0.f;
      #pragma unroll
      for (int r=0;r<4;r++){
        float v = acc[wt*4+s][r] + bv;
        if (act==1) v = fmaxf(v, 0.f);
        else if (act==2) v = gelu_f(v);
        if (OM == 1){
          const int m = mb + r, b = m/169, tt = m%169;
          const int gate = n>>9, cblk = (n>>4)&31, jl = n&15;
          outB[(((long)tt*32 + cblk)*3 + gate)*2048 + b*16 + jl] = f2us(v);
        } else if (OM == 3){
          if (n < 32){
            const int m = mb + r, t = m/128, b2 = m%128;
            outF[((long)b2*32 + n)*169 + t] = v;
          }
        } else {
          const long oo = (long)(mb + r)*ldc + n;
          if (outF) outF[oo] = v;
          if (outB) outB[oo] = f2us(v);
        }
      }
    }
}

// conv2 implicit-im2col GEMM
__global__ __launch_bounds__(256) void gemm_conv2(
    const u16* __restrict__ C1, const u16* __restrict__ W,
    const float* __restrict__ bias, const float* __restrict__ scale, const float* __restrict__ shift,
    u16* __restrict__ outB){
  __shared__ __align__(16) u16 As[64][72];
  __shared__ __align__(16) u16 Ws[64][72];
  const int tid = threadIdx.x, wv = tid>>6, lane = tid&63;
  const int quad = lane>>4, l16 = lane&15;
  const int bm = blockIdx.y, bn = blockIdx.x;
  f32x4 acc[4];
  #pragma unroll
  for (int i=0;i<4;i++) acc[i] = (f32x4){0.f,0.f,0.f,0.f};
  const int sm = tid>>2, sk = (tid&3)<<4;
  const int g = bm*64 + sm, n_ = g/9, pos = g%9, py = pos/3, px = pos%3;
  const long wrow = (long)(bn*64 + sm)*576;
  for (int tap = 0; tap < 9; tap++){
    const int kb = tap*64;
    const long aoff = ((long)n_*25 + (py + tap/3)*5 + (px + tap%3))*64 + sk;
    int4 a0 = *(const int4*)(C1 + aoff);
    int4 a1 = *(const int4*)(C1 + aoff + 8);
    int4 w0 = *(const int4*)(W + wrow + kb + sk);
    int4 w1 = *(const int4*)(W + wrow + kb + sk + 8);
    *(int4*)&As[sm][sk]   = a0;  *(int4*)&As[sm][sk+8] = a1;
    *(int4*)&Ws[sm][sk]   = w0;  *(int4*)&Ws[sm][sk+8] = w1;
    __syncthreads();
    #pragma unroll
    for (int ks = 0; ks < 64; ks += 32){
      bf16x8 af = *(const bf16x8*)(&As[wv*16 + l16][ks + quad*8]);
      #pragma unroll
      for (int nt=0; nt<4; nt++){
        bf16x8 bfv = *(const bf16x8*)(&Ws[nt*16 + l16][ks + quad*8]);
        acc[nt] = __builtin_amdgcn_mfma_f32_16x16x32_bf16(af, bfv, acc[nt], 0, 0, 0);
      }
    }
    __syncthreads();
  }
  const int mb = bm*64 + wv*16 + quad*4;
  #pragma unroll
  for (int nt=0; nt<4; nt++){
    const int n = bn*64 + nt*16 + l16;
    const float bv = bias[n], sc = scale[n], sh = shift[n];
    #pragma unroll
    for (int r=0;r<4;r++){
      float v = (acc[nt][r] + bv)*sc + sh;
      outB[(long)(mb + r)*128 + n] = f2us(gelu_f(v));
    }
  }
}

// tokens -> h bf16 [86528][256]; fills slots 0..2
__global__ void token_kernel(const int* __restrict__ tm, const float* __restrict__ te,
                             const float* __restrict__ mv, const float* __restrict__ pos,
                             u16* __restrict__ hB){
  const int n = blockIdx.x, k = threadIdx.x;
  const int b = n/169, p = n%169;
  const int prev = (p==0) ? 31 : tm[b*169 + p - 1];
  const long r0 = (long)n*1024;
  hB[r0 + k]        = f2us(te[prev*256 + k]);
  hB[r0 + 256 + k]  = f2us(mv[b*256 + k]);
  hB[r0 + 512 + k]  = f2us(pos[p*256 + k]);
}

// attention
__global__ __launch_bounds__(256) void attn_kernel(const u16* __restrict__ qkv, u16* o){
  const int n = blockIdx.x*4 + (threadIdx.x>>6);
  const int lane = threadIdx.x & 63;
  float qv[4][2][2], kv[4][2][2], vv[4][2][2];
  #pragma unroll
  for (int tok=0; tok<4; tok++){
    const long rb = (long)(n*4+tok)*768;
    #pragma unroll
    for (int h=0; h<2; h++){
      unsigned u;
      u = *(const unsigned*)(qkv + rb +        h*128 + 2*lane); qv[tok][h][0]=us2f(u&0xffff); qv[tok][h][1]=us2f(u>>16);
      u = *(const unsigned*)(qkv + rb + 256 +  h*128 + 2*lane); kv[tok][h][0]=us2f(u&0xffff); kv[tok][h][1]=us2f(u>>16);
      u = *(const unsigned*)(qkv + rb + 512 +  h*128 + 2*lane); vv[tok][h][0]=us2f(u&0xffff); vv[tok][h][1]=us2f(u>>16);
    }
  }
  float sc[2][4][4];
  #pragma unroll
  for (int h=0; h<2; h++)
    #pragma unroll
    for (int qt=0; qt<4; qt++)
      #pragma unroll
      for (int kt=0; kt<4; kt++){
        float p_ = qv[qt][h][0]*kv[kt][h][0] + qv[qt][h][1]*kv[kt][h][1];
        for (int off=32; off; off>>=1) p_ += __shfl_xor(p_, off);
        sc[h][qt][kt] = p_ * 0.08838834764831845f;
      }
  #pragma unroll
  for (int h=0; h<2; h++)
    #pragma unroll
    for (int qt=0; qt<4; qt++){
      float m = fmaxf(fmaxf(sc[h][qt][0],sc[h][qt][1]),fmaxf(sc[h][qt][2],sc[h][qt][3]));
      float s = 0.f;
      #pragma unroll
      for (int kt=0; kt<4; kt++){ sc[h][qt][kt] = expf(sc[h][qt][kt]-m); s += sc[h][qt][kt]; }
      float inv = 1.f/s;
      #pragma unroll
      for (int kt=0; kt<4; kt++) sc[h][qt][kt] *= inv;
    }
  #pragma unroll
  for (int qt=0; qt<4; qt++)
    #pragma unroll
    for (int h=0; h<2; h++){
      float o0=0.f, o1=0.f;
      #pragma unroll
      for (int kt=0; kt<4; kt++){ o0 += sc[h][qt][kt]*vv[kt][h][0]; o1 += sc[h][qt][kt]*vv[kt][h][1]; }
      unsigned u = (unsigned)f2us(o0) | ((unsigned)f2us(o1)<<16);
      *(unsigned*)(o + (long)(n*4+qt)*256 + h*128 + 2*lane) = u;
    }
}

// LayerNorm — head fcln(+gelu) only
template<int NPL>
__global__ __launch_bounds__(256) void ln_kernel(
    const u16* __restrict__ delta, const u16* __restrict__ base,
    const float* __restrict__ g, const float* __restrict__ b,
    u16* __restrict__ out, int do_gelu){
  const int D = NPL*64;
  const int row = blockIdx.x*4 + (threadIdx.x>>6);
  const int lane = threadIdx.x & 63;
  const long ro = (long)row*D;
  float x[NPL];
  float s = 0.f;
  #pragma unroll
  for (int i=0;i<NPL;i++){
    float v = us2f(delta[ro + i*64 + lane]);
    if (base) v += us2f(base[ro + i*64 + lane]);
    x[i] = v; s += v;
  }
  for (int off=32; off; off>>=1) s += __shfl_xor(s, off);
  const float mean = s / D;
  float var = 0.f;
  #pragma unroll
  for (int i=0;i<NPL;i++){ float dd = x[i]-mean; var += dd*dd; }
  for (int off=32; off; off>>=1) var += __shfl_xor(var, off);
  const float rs = rsqrtf(var/D + 1e-5f);
  #pragma unroll
  for (int i=0;i<NPL;i++){
    float y = (x[i]-mean)*rs*g[i*64+lane] + b[i*64+lane];
    if (do_gelu) y = gelu_f(y);
    out[ro + i*64 + lane] = f2us(y);
  }
}

// GRU v7 (R11-proven): distributed per-WG flags, wide sc0/sc1 h exchange.
__global__ __launch_bounds__(256) void gru_kernel(
    const u16* __restrict__ gix, const float* __restrict__ whh,
    const float* __restrict__ bhh, u16* __restrict__ hx, u16* __restrict__ hs,
    unsigned* __restrict__ bar){
  __shared__ __align__(16) u16 Wl[48][520];
  __shared__ __align__(16) u16 hbuf[2048];
  const int c = blockIdx.x, tid = threadIdx.x;
  const int wv = tid>>6, lane = tid&63, quad = lane>>4, l16 = lane&15;
  for (int idx = tid; idx < 48*512; idx += 256){
    int g = idx >> 9, k = idx & 511;
    int gate = g >> 4, jl = g & 15;
    Wl[g][k] = f2us(whh[((gate<<9) + (c<<4) + jl)*512 + k]);
  }
  const int j = (c<<4) + l16;
  const float bh_r = bhh[j], bh_z = bhh[512+j], bh_n = bhh[1024+j];
  __syncthreads();
  float hold[2][4] = {{0.f,0.f,0.f,0.f},{0.f,0.f,0.f,0.f}};
  const int jlo = (quad&1)*8, jhiadd = quad>>1;
  for (int t=0; t<169; t++){
    const u16* gbase = gix + ((long)t*32 + c)*3*2048;
    float gr_[2][4], gz_[2][4], gn_[2][4];
    #pragma unroll
    for (int mt=0; mt<2; mt++)
      #pragma unroll
      for (int r=0; r<4; r++){
        const int b = (2*wv+mt)*16 + quad*4 + r;
        gr_[mt][r] = us2f(gbase[       b*16 + l16]);
        gz_[mt][r] = us2f(gbase[2048 + b*16 + l16]);
        gn_[mt][r] = us2f(gbase[4096 + b*16 + l16]);
      }
    if (t>0){
      if (tid < 32){
        const u32* fp = bar + tid*16;
        u32 v;
        do {
          asm volatile("global_load_dword %0, %1, off sc0 sc1" : "=v"(v) : "v"(fp));
          asm volatile("s_waitcnt vmcnt(0)" ::: "memory");
        } while ((int)v < t);
      }
      __syncthreads();
    }
    f32x4 acc[2][3];
    #pragma unroll
    for (int mt=0; mt<2; mt++)
      #pragma unroll
      for (int g3=0; g3<3; g3++) acc[mt][g3] = (f32x4){0.f,0.f,0.f,0.f};
    if (t>0){
      const long tb = (long)(t-1)*65536;
      const int b0 = (2*wv+0)*16 + l16, b1 = (2*wv+1)*16 + l16;
      bf16x8 av0[16], av1[16];
      #pragma unroll
      for (int ii=0; ii<16; ii++){
        const long off = tb + (long)(ii*2 + jhiadd)*2048 + jlo;
        const u16* p0 = hx + off + b0*16;
        const u16* p1 = hx + off + b1*16;
        asm volatile("global_load_dwordx4 %0, %1, off sc0 sc1" : "=v"(av0[ii]) : "v"(p0));
        asm volatile("global_load_dwordx4 %0, %1, off sc0 sc1" : "=v"(av1[ii]) : "v"(p1));
      }
      asm volatile("s_waitcnt vmcnt(0)" ::: "memory");
      #pragma unroll
      for (int ii=0; ii<16; ii++){
        asm volatile("" : "+v"(av0[ii]));
        asm volatile("" : "+v"(av1[ii]));
      }
      #pragma unroll
      for (int ii=0; ii<16; ii++){
        const int ks = ii*32;
        #pragma unroll
        for (int g3=0; g3<3; g3++){
          bf16x8 bfv = *(const bf16x8*)(&Wl[g3*16 + l16][ks + quad*8]);
          acc[0][g3] = __builtin_amdgcn_mfma_f32_16x16x32_bf16(av0[ii], bfv, acc[0][g3], 0,0,0);
          acc[1][g3] = __builtin_amdgcn_mfma_f32_16x16x32_bf16(av1[ii], bfv, acc[1][g3], 0,0,0);
        }
      }
    }
    u16 hbv[2][4];
    #pragma unroll
    for (int mt=0; mt<2; mt++)
      #pragma unroll
      for (int r=0; r<4; r++){
        const int b = (2*wv+mt)*16 + quad*4 + r;
        float rr = sigm_f(gr_[mt][r] + acc[mt][0][r] + bh_r);
        float zz = sigm_f(gz_[mt][r] + acc[mt][1][r] + bh_z);
        float nn = tanhf (gn_[mt][r] + rr*(acc[mt][2][r] + bh_n));
        float h = (1.f-zz)*nn + zz*hold[mt][r];
        hold[mt][r] = h;
        hbv[mt][r] = f2us(h);
        hbuf[b*16 + l16] = hbv[mt][r];
      }
    __syncthreads();
    {
      u16* dst = hx + (long)t*65536 + c*2048 + tid*8;
      u32x4 val = *(const u32x4*)((const u32*)hbuf + tid*4);
      asm volatile("global_store_dwordx4 %0, %1, off sc0 sc1" :: "v"(dst), "v"(val) : "memory");
    }
    asm volatile("s_waitcnt vmcnt(0)" ::: "memory");
    __syncthreads();
    if (tid==0){
      u32 tv = (u32)(t+1);
      const u32* fp = bar + c*16;
      asm volatile("global_store_dword %0, %1, off sc0 sc1" :: "v"(fp), "v"(tv) : "memory");
    }
    // off-critical-path row-major hs for the head GEMM
    #pragma unroll
    for (int mt=0; mt<2; mt++)
      #pragma unroll
      for (int r=0; r<4; r++){
        const int b = (2*wv+mt)*16 + quad*4 + r;
        hs[((long)(t*128 + b))*512 + j] = hbv[mt][r];
      }
  }
}

// ---------------------------------------------------------------- host
extern "C" void kernel_launch(void* const* d_in, const int* in_sizes, int n_in,
                              void* d_out, int out_size, void* d_ws, size_t ws_size,
                              hipStream_t stream){
  (void)in_sizes; (void)n_in; (void)out_size;
  const float* map_vec = (const float*)d_in[0];
  const int*   tm      = (const int*)  d_in[1];
  const float* mv_w  = (const float*)d_in[2];
  const float* mv_b  = (const float*)d_in[3];
  const float* te    = (const float*)d_in[4];
  const float* row_e = (const float*)d_in[5];
  const float* col_e = (const float*)d_in[6];
  const float* pos_w = (const float*)d_in[7];
  const float* pos_b = (const float*)d_in[8];
  const float* c1_w  = (const float*)d_in[9];
  const float* c1_b  = (const float*)d_in[10];
  const float* bn1_g = (const float*)d_in[11];
  const float* bn1_b = (const float*)d_in[12];
  const float* c2_w  = (const float*)d_in[13];
  const float* c2_b  = (const float*)d_in[14];
  const float* bn2_g = (const float*)d_in[15];
  const float* bn2_b = (const float*)d_in[16];
  const float* pf_w  = (const float*)d_in[17];
  const float* pf_b  = (const float*)d_in[18];
  const float* qkv_w = (const float*)d_in[19];
  const float* qkv_b = (const float*)d_in[20];
  const float* out_w = (const float*)d_in[21];
  const float* out_b = (const float*)d_in[22];
  const float* ln1_g = (const float*)d_in[23];
  const float* ln1_b = (const float*)d_in[24];
  const float* ff1_w = (const float*)d_in[25];
  const float* ff1_b = (const float*)d_in[26];
  const float* ff2_w = (const float*)d_in[27];
  const float* ff2_b = (const float*)d_in[28];
  const float* ln2_g = (const float*)d_in[29];
  const float* ln2_b = (const float*)d_in[30];
  const float* g_wih = (const float*)d_in[31];
  const float* g_whh = (const float*)d_in[32];
  const float* g_bih = (const float*)d_in[33];
  const float* g_bhh = (const float*)d_in[34];
  const float* fc1_w = (const float*)d_in[35];
  const float* fc1_b = (const float*)d_in[36];
  const float* fln_g = (const float*)d_in[37];
  const float* fln_b = (const float*)d_in[38];
  const float* fc2_w = (const float*)d_in[39];
  const float* fc2_b = (const float*)d_in[40];

  char* ws = (char*)d_ws;
  constexpr size_t O_BAR  = 0;                         // 2KB: 32 flags @64B
  constexpr size_t O_QKVW = 2048;
  constexpr size_t O_OUTW = O_QKVW + 1179648;
  constexpr size_t O_FF1W = O_OUTW + 393216;
  constexpr size_t O_FF2W = O_FF1W + 393216;
  constexpr size_t O_WIHW = O_FF2W + 393216;
  constexpr size_t O_FC1W = O_WIHW + 786432;
  constexpr size_t O_PFW  = O_FC1W + 524288;
  constexpr size_t O_W2K  = O_PFW  + 589824;
  constexpr size_t O_FC2W = O_W2K  + 147456;
  constexpr size_t O_FC2B = O_FC2W + 65536;
  constexpr size_t O_W1T  = O_FC2B + 256;
  constexpr size_t O_T2   = O_W1T  + 73728;
  constexpr size_t O_S2   = O_T2   + 1081600;
  constexpr size_t O_MV   = O_S2   + 512;
  constexpr size_t O_POS  = O_MV   + 131072;
  constexpr size_t O_ECLS = O_POS  + 173056;
  constexpr size_t O_R0   = ((O_ECLS + 540800 + 255)/256)*256;
  constexpr size_t R0_SZ  = 44302336;
  constexpr size_t O_R1   = O_R0 + R0_SZ;
  constexpr size_t R1_SZ  = 44302336;
  constexpr size_t O_R2   = O_R1 + R1_SZ;
  constexpr size_t R2_SZ  = 33226752;
  constexpr size_t ARENA_END = O_R2 + R2_SZ;
  if (ws_size < ARENA_END) return;
  const size_t O_HB    = O_R0;
  const size_t O_HX    = O_R0;
  const size_t O_HS    = O_R0 + 22151168;
  const size_t O_C1OUT = O_R1;
  const size_t O_OBUF  = O_R1;
  const size_t O_GIX   = O_R1;
  const size_t O_Y1    = O_R1;
  const size_t O_YB    = O_R1 + 22151168;
  const size_t O_C2OUT = O_R2;
  const size_t O_QKVC  = O_R2;

  PrepArgs pa;
  pa.qkv_w=qkv_w; pa.out_w=out_w; pa.ff1_w=ff1_w; pa.ff2_w=ff2_w; pa.g_wih=g_wih;
  pa.fc1_w=fc1_w; pa.pf_w=pf_w; pa.c2_w=c2_w; pa.fc2_w=fc2_w; pa.fc2_b=fc2_b;
  pa.c1_w=c1_w; pa.c1_b=c1_b; pa.bn2_g=bn2_g;
  pa.map_vec=map_vec; pa.mv_w=mv_w; pa.mv_b=mv_b; pa.row_e=row_e; pa.col_e=col_e;
  pa.pos_w=pos_w; pa.pos_b=pos_b; pa.tm=tm;
  pa.qkvw_d=(u16*)(ws+O_QKVW); pa.outw_d=(u16*)(ws+O_OUTW); pa.ff1w_d=(u16*)(ws+O_FF1W);
  pa.ff2w_d=(u16*)(ws+O_FF2W); pa.wihw_d=(u16*)(ws+O_WIHW); pa.fc1w_d=(u16*)(ws+O_FC1W);
  pa.pfw_d=(u16*)(ws+O_PFW); pa.w2k_d=(u16*)(ws+O_W2K); pa.fc2w_d=(u16*)(ws+O_FC2W);
  pa.fc2b_d=(float*)(ws+O_FC2B); pa.w1t_d=(float*)(ws+O_W1T); pa.t2_d=(float*)(ws+O_T2);
  pa.s2_d=(float*)(ws+O_S2); pa.mv_d=(float*)(ws+O_MV); pa.pos_d=(float*)(ws+O_POS);
  pa.ecls_d=(u8*)(ws+O_ECLS); pa.bar=(unsigned*)(ws+O_BAR);
  prep_kernel<<<PREP_GRID, 256, 0, stream>>>(pa);

  token_kernel<<<21632, 256, 0, stream>>>(tm, te, (const float*)(ws+O_MV), (const float*)(ws+O_POS),
      (u16*)(ws+O_HB));

  for (int cc = 0; cc < 2; cc++){
    const int nbase = cc*10816;
    conv1_kernel<<<338, 256, 0, stream>>>((const u8*)(ws+O_ECLS), (const float*)(ws+O_W1T),
        (const float*)(ws+O_T2), bn1_g, bn1_b, (u16*)(ws+O_C1OUT), nbase);
    gemm_conv2<<<dim3(2,1521), 256, 0, stream>>>((const u16*)(ws+O_C1OUT), (const u16*)(ws+O_W2K),
        c2_b, (const float*)(ws+O_S2), bn2_b, (u16*)(ws+O_C2OUT));
    gemm_bt<4,0><<<dim3(1,169), 256, 0, stream>>>((const u16*)(ws+O_C2OUT), 1152, (const u16*)(ws+O_PFW),
        pf_b, nullptr, (u16*)(ws+O_HB) + (size_t)nbase*1024 + 768, 1024, 256, 1152, 0,
        nullptr, nullptr, nullptr);
  }

  for (int l=0; l<3; l++){
    for (int cc = 0; cc < 4; cc++){
      gemm_bt<4,0><<<dim3(3,338), 256, 0, stream>>>((const u16*)(ws+O_HB) + (size_t)cc*21632*256, 256,
          (const u16*)(ws+O_QKVW) + (size_t)l*768*256, qkv_b + l*768,
          nullptr, (u16*)(ws+O_QKVC), 768, 768, 256, 0, nullptr, nullptr, nullptr);
      attn_kernel<<<1352, 256, 0, stream>>>((const u16*)(ws+O_QKVC),
          (u16*)(ws+O_OBUF) + (size_t)cc*5408*4*256);
    }
    gemm_bt<4,2><<<dim3(1,1352), 256, 0, stream>>>((const u16*)(ws+O_OBUF), 256,
        (const u16*)(ws+O_OUTW) + (size_t)l*256*256, out_b + l*256,
        nullptr, (u16*)(ws+O_HB), 256, 256, 256, 0,
        (const u16*)(ws+O_HB), ln1_g + l*256, ln1_b + l*256);
    gemm_bt<4,0><<<dim3(1,1352), 256, 0, stream>>>((const u16*)(ws+O_HB), 256,
        (const u16*)(ws+O_FF1W) + (size_t)l*256*256, ff1_b + l*256,
        nullptr, (u16*)(ws+O_OBUF), 256, 256, 256, 1, nullptr, nullptr, nullptr);
    gemm_bt<4,2><<<dim3(1,1352), 256, 0, stream>>>((const u16*)(ws+O_OBUF), 256,
        (const u16*)(ws+O_FF2W) + (size_t)l*256*256, ff2_b + l*256,
        nullptr, (u16*)(ws+O_HB), 256, 256, 256, 0,
        (const u16*)(ws+O_HB), ln2_g + l*256, ln2_b + l*256);
  }

  // GRU input projection -> swizzled giX (OM=1), M=21632 rows (BM=64 -> 338 blocks)
  gemm_bt<4,1><<<dim3(6,338), 256, 0, stream>>>((const u16*)(ws+O_HB), 1024, (const u16*)(ws+O_WIHW),
      g_bih, nullptr, (u16*)(ws+O_GIX), 1536, 1536, 256, 0, nullptr, nullptr, nullptr);
  gru_kernel<<<32, 256, 0, stream>>>((const u16*)(ws+O_GIX), g_whh, g_bhh,
      (u16*)(ws+O_HX), (u16*)(ws+O_HS), (unsigned*)(ws+O_BAR));

  // head (rows m = t*128+b)
  gemm_bt<4,0><<<dim3(2,338), 256, 0, stream>>>((const u16*)(ws+O_HS), 512, (const u16*)(ws+O_FC1W),
      fc1_b, nullptr, (u16*)(ws+O_Y1), 512, 512, 512, 0, nullptr, nullptr, nullptr);
  ln_kernel<8><<<5408, 256, 0, stream>>>((const u16*)(ws+O_Y1), nullptr, fln_g, fln_b,
      (u16*)(ws+O_YB), 1);
  gemm_bt<1,3><<<dim3(1,338), 256, 0, stream>>>((const u16*)(ws+O_YB), 512, (const u16*)(ws+O_FC2W),
      (const float*)(ws+O_FC2B), (float*)d_out, nullptr, 64, 64, 512, 0, nullptr, nullptr, nullptr);
}

// Round 13
// 2886.538 us; speedup vs baseline: 1.1658x; 1.0081x over previous
//
#include <hip/hip_runtime.h>
#include <hip/hip_bf16.h>

typedef unsigned short u16;
typedef unsigned char u8;
typedef unsigned int u32;
typedef __attribute__((ext_vector_type(8))) short bf16x8;
typedef __attribute__((ext_vector_type(4))) float f32x4;
typedef __attribute__((ext_vector_type(4))) unsigned int u32x4;

__device__ __forceinline__ float us2f(u16 u){ return __uint_as_float(((unsigned)u)<<16); }
__device__ __forceinline__ u16 f2us(float f){
  __hip_bfloat16 h = __float2bfloat16(f);
  union { __hip_bfloat16 b; u16 s; } cv; cv.b = h; return cv.s;
}
__device__ __forceinline__ float gelu_f(float v){ return 0.5f*v*(1.f+erff(v*0.70710678118654752f)); }
__device__ __forceinline__ float sigm_f(float v){ return 1.f/(1.f+expf(-v)); }

#define BNSC 0.9999950000374997f  /* 1/sqrt(1+1e-5) */

// ---------------------------------------------------------------- fused prep
struct PrepArgs {
  const float *qkv_w, *out_w, *ff1_w, *ff2_w, *g_wih, *fc1_w, *pf_w, *c2_w, *fc2_w, *fc2_b;
  const float *c1_w, *c1_b, *bn2_g;
  const float *map_vec, *mv_w, *mv_b, *row_e, *col_e, *pos_w, *pos_b;
  const int *tm;
  u16 *qkvw_d, *outw_d, *ff1w_d, *ff2w_d, *wihw_d, *fc1w_d, *pfw_d, *w2k_d, *fc2w_d;
  float *fc2b_d, *w1t_d, *t2_d, *s2_d, *mv_d, *pos_d;
  u8 *ecls_d;
  unsigned *bar;
};
#define SB_QKV 2304
#define SB_O   768
#define SB_WIH 1536
#define SB_FC1 1024
#define SB_PF  1152
#define SB_W2  288
#define SB_FC2 128
#define SB_W1T 72
#define SB_T2  1057
#define SB_MV  128
#define SB_POS 169
#define SB_EC  2113
#define PREP_GRID (1+SB_QKV+3*SB_O+SB_WIH+SB_FC1+SB_PF+SB_W2+SB_FC2+SB_W1T+SB_T2+SB_MV+SB_POS+SB_EC)

__global__ __launch_bounds__(256) void prep_kernel(PrepArgs a){
  int bb = blockIdx.x; const int tid = threadIdx.x;
  if (bb < 1){
    a.bar[tid] = 0u; a.bar[256+tid] = 0u;       // 2KB flag region (128 flags @16B)
    if (tid < 128) a.s2_d[tid] = a.bn2_g[tid]*BNSC;
    return;
  } bb -= 1;
  if (bb < SB_QKV){ int i = bb*256+tid; a.qkvw_d[i] = f2us(a.qkv_w[i]); return; } bb -= SB_QKV;
  if (bb < SB_O){ int i = bb*256+tid; a.outw_d[i] = f2us(a.out_w[i]); return; } bb -= SB_O;
  if (bb < SB_O){ int i = bb*256+tid; a.ff1w_d[i] = f2us(a.ff1_w[i]); return; } bb -= SB_O;
  if (bb < SB_O){ int i = bb*256+tid; a.ff2w_d[i] = f2us(a.ff2_w[i]); return; } bb -= SB_O;
  if (bb < SB_WIH){ int i = bb*256+tid; a.wihw_d[i] = f2us(a.g_wih[i]); return; } bb -= SB_WIH;
  if (bb < SB_FC1){ int i = bb*256+tid; a.fc1w_d[i] = f2us(a.fc1_w[i]); return; } bb -= SB_FC1;
  if (bb < SB_PF){
    int i = bb*256+tid;
    int o = i/1152, kp = i%1152, pos = kp>>7, c = kp&127;
    a.pfw_d[i] = f2us(a.pf_w[o*1152 + c*9 + pos]); return;
  } bb -= SB_PF;
  if (bb < SB_W2){
    int i = bb*256+tid;
    int o = i/576, k = i%576, tap = k>>6, ic = k&63, ty = tap/3, tx = tap%3;
    a.w2k_d[i] = f2us(a.c2_w[((o*64 + ic)*3 + ty)*3 + tx]); return;
  } bb -= SB_W2;
  if (bb < SB_FC2){
    int i = bb*256+tid;
    int o = i>>9, k = i&511;
    a.fc2w_d[i] = (o<32) ? f2us(a.fc2_w[o*512+k]) : (u16)0;
    if (i < 64) a.fc2b_d[i] = (i<32) ? a.fc2_b[i] : 0.f;
    return;
  } bb -= SB_FC2;
  if (bb < SB_W1T){
    int i = bb*256+tid;
    int c = i/576, r = i%576, tap = r>>6, o = r&63;
    a.w1t_d[i] = a.c1_w[(o*33 + c)*9 + tap]; return;
  } bb -= SB_W1T;
  if (bb < SB_T2){
    int i = bb*256+tid; if (i >= 169*25*64) return;
    int blk = i/64, o = i%64;
    int p = blk/25, op = blk%25, oy = op/5, ox = op%5;
    int yp = p/13, xp = p%13;
    float acc = a.c1_b[o];
    for (int dy=0; dy<3; dy++) for (int dx=0; dx<3; dx++){
      int Y = oy+dy-1, X = ox+dx-1;
      if (Y<0||Y>4||X<0||X>4) continue;
      int rr = yp + Y - 4, cc = xp + X - 2;
      bool m = (rr>=0) && (cc>=0) && (cc<13) && !(Y==4 && X>=2);
      if (m) acc += a.c1_w[(o*33 + 32)*9 + dy*3 + dx];
    }
    a.t2_d[((long)p*25 + op)*64 + o] = acc; return;
  } bb -= SB_T2;
  if (bb < SB_MV){
    int i = bb*256+tid;
    int bi = i>>8, o = i&255;
    float acc = a.mv_b[o];
    for (int k=0;k<32;k++) acc += a.map_vec[bi*32+k]*a.mv_w[o*32+k];
    a.mv_d[i] = acc; return;
  } bb -= SB_MV;
  if (bb < SB_POS){
    int i = bb*256+tid;
    int p = i>>8, o = i&255;
    int y = p/13, x = p%13;
    const float* wr = a.pos_w + o*512;
    float acc = a.pos_b[o];
    for (int k=0;k<256;k++) acc += a.row_e[y*256+k]*wr[k];
    for (int k=0;k<256;k++) acc += a.col_e[x*256+k]*wr[256+k];
    a.pos_d[i] = acc; return;
  } bb -= SB_POS;
  {
    int id = bb*256+tid; if (id >= 21632*25) return;
    int n = id/25, q = id%25, Y = q/5, X = q%5;
    int b = n/169, p = n%169, yp = p/13, xp = p%13;
    int rr = yp + X - 4, cc = xp + Y - 2;
    int val = 0;
    if (rr>=0 && cc>=0 && cc<13 && !(X==4 && Y>=2)) val = a.tm[b*169 + rr*13 + cc];
    a.ecls_d[id] = (u8)val;
  }
}

// conv1 gather + BN + gelu
__global__ __launch_bounds__(256) void conv1_kernel(
    const u8* __restrict__ ec, const float* __restrict__ w1t, const float* __restrict__ t2,
    const float* __restrict__ bn1g, const float* __restrict__ bn1b, u16* __restrict__ c1out,
    int nbase){
  __shared__ __align__(16) u16 w1s[32*9*64];
  __shared__ u8 ecs[32*25];
  const int tid = threadIdx.x, nl0 = blockIdx.x*32;
  for (int i=tid; i<32*9*64; i+=256) w1s[i] = f2us(w1t[i]);
  for (int i=tid; i<32*25;   i+=256) ecs[i] = ec[((long)nbase + nl0)*25 + i];
  __syncthreads();
  const int grp = tid>>6, o = tid&63;
  const float s1 = bn1g[o]*BNSC, t1 = bn1b[o];
  for (int it = grp; it < 800; it += 4){
    const int nl = it/25, op = it%25, oy = op/5, ox = op%5;
    const int n = nbase + nl0 + nl, p = n%169;
    float acc = t2[((long)p*25 + op)*64 + o];
    #pragma unroll
    for (int dy=0; dy<3; dy++)
      #pragma unroll
      for (int dx=0; dx<3; dx++){
        int Y = oy+dy-1, X = ox+dx-1;
        if (Y>=0 && Y<5 && X>=0 && X<5){
          int e = ecs[nl*25 + Y*5 + X];
          acc += us2f(w1s[(e*9 + dy*3+dx)*64 + o]);
        }
      }
    c1out[((long)(nl0+nl)*25 + op)*64 + o] = f2us(gelu_f(acc*s1 + t1));
  }
}

// ----------------------------------------------- BM=64 GEMM C = A@W^T (R9-proven)
// OM 0: row-major out (in-place safe when grid.x==1)
// OM 1: giZ scatter [t][bg4][cs32][g3][jl16][bl32], m=b*169+t
// OM 2: LN epilogue (grid.x==1, N==64*NT): outB = LN(acc+bias+lbase)*lg+lb
// OM 3: head scatter: m=t*128+b2, n<32 -> outF[(b2*32+n)*169+t]
template<int NT, int OM>
__global__ __launch_bounds__(256) void gemm_bt(
    const u16* A, long lda, const u16* __restrict__ W,
    const float* __restrict__ bias,
    float* outF, u16* outB, long ldc, int N, int K, int act,
    const u16* __restrict__ lbase, const float* __restrict__ lg, const float* __restrict__ lb){
  __shared__ __align__(16) u16 As[64][72];
  __shared__ __align__(16) u16 Ws[NT][64][72];
  const int tid = threadIdx.x, wv = tid>>6, lane = tid&63;
  const int quad = lane>>4, l16 = lane&15;
  const int bm = blockIdx.y, bn = blockIdx.x;
  f32x4 acc[NT*4];
  #pragma unroll
  for (int i=0;i<NT*4;i++) acc[i] = (f32x4){0.f,0.f,0.f,0.f};
  const int sm = tid>>2, sk = (tid&3)<<4;
  const long arow = (long)(bm*64 + sm)*lda;
  for (int kb = 0; kb < K; kb += 64){
    int4 a0 = *(const int4*)(A + arow + kb + sk);
    int4 a1 = *(const int4*)(A + arow + kb + sk + 8);
    *(int4*)&As[sm][sk]   = a0;  *(int4*)&As[sm][sk+8] = a1;
    #pragma unroll
    for (int wt=0; wt<NT; wt++){
      const long wrow = (long)(bn*(64*NT) + wt*64 + sm)*K;
      int4 w0 = *(const int4*)(W + wrow + kb + sk);
      int4 w1 = *(const int4*)(W + wrow + kb + sk + 8);
      *(int4*)&Ws[wt][sm][sk]   = w0;  *(int4*)&Ws[wt][sm][sk+8] = w1;
    }
    __syncthreads();
    #pragma unroll
    for (int ks = 0; ks < 64; ks += 32){
      bf16x8 af = *(const bf16x8*)(&As[wv*16 + l16][ks + quad*8]);
      #pragma unroll
      for (int wt=0; wt<NT; wt++)
        #pragma unroll
        for (int s=0; s<4; s++){
          bf16x8 bfv = *(const bf16x8*)(&Ws[wt][s*16 + l16][ks + quad*8]);
          acc[wt*4+s] = __builtin_amdgcn_mfma_f32_16x16x32_bf16(af, bfv, acc[wt*4+s], 0, 0, 0);
        }
    }
    __syncthreads();
  }
  const int mb = bm*64 + wv*16 + quad*4;
  if (OM == 2){
    #pragma unroll
    for (int wt=0; wt<NT; wt++)
      #pragma unroll
      for (int s=0; s<4; s++){
        const int n = wt*64 + s*16 + l16;
        const float bv = bias[n];
        #pragma unroll
        for (int r=0;r<4;r++)
          acc[wt*4+s][r] = acc[wt*4+s][r] + bv + us2f(lbase[(long)(mb+r)*N + n]);
      }
    float mean[4], rstd[4];
    #pragma unroll
    for (int r=0;r<4;r++){
      float s = 0.f;
      #pragma unroll
      for (int i=0;i<NT*4;i++) s += acc[i][r];
      s += __shfl_xor(s,1); s += __shfl_xor(s,2); s += __shfl_xor(s,4); s += __shfl_xor(s,8);
      mean[r] = s / N;
      float v = 0.f;
      #pragma unroll
      for (int i=0;i<NT*4;i++){ float d = acc[i][r]-mean[r]; v += d*d; }
      v += __shfl_xor(v,1); v += __shfl_xor(v,2); v += __shfl_xor(v,4); v += __shfl_xor(v,8);
      rstd[r] = rsqrtf(v/N + 1e-5f);
    }
    #pragma unroll
    for (int wt=0; wt<NT; wt++)
      #pragma unroll
      for (int s=0; s<4; s++){
        const int n = wt*64 + s*16 + l16;
        const float gv = lg[n], bvv = lb[n];
        #pragma unroll
        for (int r=0;r<4;r++)
          outB[(long)(mb+r)*ldc + n] = f2us((acc[wt*4+s][r]-mean[r])*rstd[r]*gv + bvv);
      }
    return;
  }
  #pragma unroll
  for (int wt=0; wt<NT; wt++)
    #pragma unroll
    for (int s=0; s<4; s++){
      const int n = bn*(64*NT) + wt*64 + s*16 + l16;
      const float bv = bias ? bias[n] : 0.f;
      #pragma unroll
      for (int r=0;r<4;r++){
        float v = acc[wt*4+s][r] + bv;
        if (act==1) v = fmaxf(v, 0.f);
        else if (act==2) v = gelu_f(v);
        if (OM == 1){
          const int m = mb + r, b = m/169, tt = m%169;
          const int g = n>>9, j = n&511, cs = j>>4, jl = j&15, bg = b>>5, bl = b&31;
          outB[((((long)tt*4 + bg)*32 + cs)*48 + g*16 + jl)*32 + bl] = f2us(v);
        } else if (OM == 3){
          if (n < 32){
            const int m = mb + r, t = m/128, b2 = m%128;
            outF[((long)b2*32 + n)*169 + t] = v;
          }
        } else {
          const long oo = (long)(mb + r)*ldc + n;
          if (outF) outF[oo] = v;
          if (outB) outB[oo] = f2us(v);
        }
      }
    }
}

// conv2 implicit-im2col GEMM
__global__ __launch_bounds__(256) void gemm_conv2(
    const u16* __restrict__ C1, const u16* __restrict__ W,
    const float* __restrict__ bias, const float* __restrict__ scale, const float* __restrict__ shift,
    u16* __restrict__ outB){
  __shared__ __align__(16) u16 As[64][72];
  __shared__ __align__(16) u16 Ws[64][72];
  const int tid = threadIdx.x, wv = tid>>6, lane = tid&63;
  const int quad = lane>>4, l16 = lane&15;
  const int bm = blockIdx.y, bn = blockIdx.x;
  f32x4 acc[4];
  #pragma unroll
  for (int i=0;i<4;i++) acc[i] = (f32x4){0.f,0.f,0.f,0.f};
  const int sm = tid>>2, sk = (tid&3)<<4;
  const int g = bm*64 + sm, n_ = g/9, pos = g%9, py = pos/3, px = pos%3;
  const long wrow = (long)(bn*64 + sm)*576;
  for (int tap = 0; tap < 9; tap++){
    const int kb = tap*64;
    const long aoff = ((long)n_*25 + (py + tap/3)*5 + (px + tap%3))*64 + sk;
    int4 a0 = *(const int4*)(C1 + aoff);
    int4 a1 = *(const int4*)(C1 + aoff + 8);
    int4 w0 = *(const int4*)(W + wrow + kb + sk);
    int4 w1 = *(const int4*)(W + wrow + kb + sk + 8);
    *(int4*)&As[sm][sk]   = a0;  *(int4*)&As[sm][sk+8] = a1;
    *(int4*)&Ws[sm][sk]   = w0;  *(int4*)&Ws[sm][sk+8] = w1;
    __syncthreads();
    #pragma unroll
    for (int ks = 0; ks < 64; ks += 32){
      bf16x8 af = *(const bf16x8*)(&As[wv*16 + l16][ks + quad*8]);
      #pragma unroll
      for (int nt=0; nt<4; nt++){
        bf16x8 bfv = *(const bf16x8*)(&Ws[nt*16 + l16][ks + quad*8]);
        acc[nt] = __builtin_amdgcn_mfma_f32_16x16x32_bf16(af, bfv, acc[nt], 0, 0, 0);
      }
    }
    __syncthreads();
  }
  const int mb = bm*64 + wv*16 + quad*4;
  #pragma unroll
  for (int nt=0; nt<4; nt++){
    const int n = bn*64 + nt*16 + l16;
    const float bv = bias[n], sc = scale[n], sh = shift[n];
    #pragma unroll
    for (int r=0;r<4;r++){
      float v = (acc[nt][r] + bv)*sc + sh;
      outB[(long)(mb + r)*128 + n] = f2us(gelu_f(v));
    }
  }
}

// tokens -> h bf16 [86528][256]; fills slots 0..2
__global__ void token_kernel(const int* __restrict__ tm, const float* __restrict__ te,
                             const float* __restrict__ mv, const float* __restrict__ pos,
                             u16* __restrict__ hB){
  const int n = blockIdx.x, k = threadIdx.x;
  const int b = n/169, p = n%169;
  const int prev = (p==0) ? 31 : tm[b*169 + p - 1];
  const long r0 = (long)n*1024;
  hB[r0 + k]        = f2us(te[prev*256 + k]);
  hB[r0 + 256 + k]  = f2us(mv[b*256 + k]);
  hB[r0 + 512 + k]  = f2us(pos[p*256 + k]);
}

// attention
__global__ __launch_bounds__(256) void attn_kernel(const u16* __restrict__ qkv, u16* o){
  const int n = blockIdx.x*4 + (threadIdx.x>>6);
  const int lane = threadIdx.x & 63;
  float qv[4][2][2], kv[4][2][2], vv[4][2][2];
  #pragma unroll
  for (int tok=0; tok<4; tok++){
    const long rb = (long)(n*4+tok)*768;
    #pragma unroll
    for (int h=0; h<2; h++){
      unsigned u;
      u = *(const unsigned*)(qkv + rb +        h*128 + 2*lane); qv[tok][h][0]=us2f(u&0xffff); qv[tok][h][1]=us2f(u>>16);
      u = *(const unsigned*)(qkv + rb + 256 +  h*128 + 2*lane); kv[tok][h][0]=us2f(u&0xffff); kv[tok][h][1]=us2f(u>>16);
      u = *(const unsigned*)(qkv + rb + 512 +  h*128 + 2*lane); vv[tok][h][0]=us2f(u&0xffff); vv[tok][h][1]=us2f(u>>16);
    }
  }
  float sc[2][4][4];
  #pragma unroll
  for (int h=0; h<2; h++)
    #pragma unroll
    for (int qt=0; qt<4; qt++)
      #pragma unroll
      for (int kt=0; kt<4; kt++){
        float p_ = qv[qt][h][0]*kv[kt][h][0] + qv[qt][h][1]*kv[kt][h][1];
        for (int off=32; off; off>>=1) p_ += __shfl_xor(p_, off);
        sc[h][qt][kt] = p_ * 0.08838834764831845f;
      }
  #pragma unroll
  for (int h=0; h<2; h++)
    #pragma unroll
    for (int qt=0; qt<4; qt++){
      float m = fmaxf(fmaxf(sc[h][qt][0],sc[h][qt][1]),fmaxf(sc[h][qt][2],sc[h][qt][3]));
      float s = 0.f;
      #pragma unroll
      for (int kt=0; kt<4; kt++){ sc[h][qt][kt] = expf(sc[h][qt][kt]-m); s += sc[h][qt][kt]; }
      float inv = 1.f/s;
      #pragma unroll
      for (int kt=0; kt<4; kt++) sc[h][qt][kt] *= inv;
    }
  #pragma unroll
  for (int qt=0; qt<4; qt++)
    #pragma unroll
    for (int h=0; h<2; h++){
      float o0=0.f, o1=0.f;
      #pragma unroll
      for (int kt=0; kt<4; kt++){ o0 += sc[h][qt][kt]*vv[kt][h][0]; o1 += sc[h][qt][kt]*vv[kt][h][1]; }
      unsigned u = (unsigned)f2us(o0) | ((unsigned)f2us(o1)<<16);
      *(unsigned*)(o + (long)(n*4+qt)*256 + h*128 + 2*lane) = u;
    }
}

// LayerNorm — head fcln(+gelu) only
template<int NPL>
__global__ __launch_bounds__(256) void ln_kernel(
    const u16* __restrict__ delta, const u16* __restrict__ base,
    const float* __restrict__ g, const float* __restrict__ b,
    u16* __restrict__ out, int do_gelu){
  const int D = NPL*64;
  const int row = blockIdx.x*4 + (threadIdx.x>>6);
  const int lane = threadIdx.x & 63;
  const long ro = (long)row*D;
  float x[NPL];
  float s = 0.f;
  #pragma unroll
  for (int i=0;i<NPL;i++){
    float v = us2f(delta[ro + i*64 + lane]);
    if (base) v += us2f(base[ro + i*64 + lane]);
    x[i] = v; s += v;
  }
  for (int off=32; off; off>>=1) s += __shfl_xor(s, off);
  const float mean = s / D;
  float var = 0.f;
  #pragma unroll
  for (int i=0;i<NPL;i++){ float dd = x[i]-mean; var += dd*dd; }
  for (int off=32; off; off>>=1) var += __shfl_xor(var, off);
  const float rs = rsqrtf(var/D + 1e-5f);
  #pragma unroll
  for (int i=0;i<NPL;i++){
    float y = (x[i]-mean)*rs*g[i*64+lane] + b[i*64+lane];
    if (do_gelu) y = gelu_f(y);
    out[ro + i*64 + lane] = f2us(y);
  }
}

// GRU v8: 128 WGs x 128 thr. WG (bg=c>>5, cs=c&31) owns batches [bg*32,+32), cols [cs*16,+16).
// Sync only within batch group (32 producers). Exchange hxY[t][bg][b_local 32][512].
// giZ[t][bg][cs][g][jl16][bl32] pre-swizzled by gi-GEMM.
__global__ __launch_bounds__(128) void gru_kernel(
    const u16* __restrict__ giz, const float* __restrict__ whh,
    const float* __restrict__ bhh, u16* __restrict__ hx, u16* __restrict__ hs,
    unsigned* __restrict__ bar){
  __shared__ __align__(16) u16 Wl[48][520];
  __shared__ __align__(16) u16 hbuf[32][16];
  const int c = blockIdx.x, tid = threadIdx.x;
  const int bg = c>>5, cs = c&31;
  const int wv = tid>>6, lane = tid&63, quad = lane>>4, l16 = lane&15;
  for (int idx = tid; idx < 48*512; idx += 128){
    int rr = idx >> 9, k = idx & 511;
    int gate = rr >> 4, jl = rr & 15;
    Wl[rr][k] = f2us(whh[((gate<<9) + (cs<<4) + jl)*512 + k]);
  }
  const int j = (cs<<4) + l16;
  const float bh_r = bhh[j], bh_z = bhh[512+j], bh_n = bhh[1024+j];
  __syncthreads();
  float hold[4] = {0.f,0.f,0.f,0.f};
  for (int t=0; t<169; t++){
    // prefetch gi (cached loads; 3KB contiguous per WG)
    const u16* gbase = giz + (((long)t*4 + bg)*32 + cs)*1536;
    float gr_[4], gz_[4], gn_[4];
    #pragma unroll
    for (int r=0; r<4; r++){
      const int bl = wv*16 + quad*4 + r;
      gr_[r] = us2f(gbase[(0*16 + l16)*32 + bl]);
      gz_[r] = us2f(gbase[(1*16 + l16)*32 + bl]);
      gn_[r] = us2f(gbase[(2*16 + l16)*32 + bl]);
    }
    if (t>0){
      if (tid < 32){
        const u32* fp = bar + (bg*32 + tid)*4;   // 16B-spaced flags
        u32 v;
        do {
          asm volatile("global_load_dword %0, %1, off sc0 sc1" : "=v"(v) : "v"(fp));
          asm volatile("s_waitcnt vmcnt(0)" ::: "memory");
        } while ((int)v < t);
      }
      __syncthreads();
    }
    f32x4 acc[3];
    #pragma unroll
    for (int g3=0; g3<3; g3++) acc[g3] = (f32x4){0.f,0.f,0.f,0.f};
    if (t>0){
      const long tb = ((long)(t-1)*4 + bg)*16384;
      const int bl = wv*16 + l16;             // A row = local batch
      bf16x8 av[16];
      #pragma unroll
      for (int ks=0; ks<16; ks++){
        const u16* p0 = hx + tb + bl*512 + ks*32 + quad*8;
        asm volatile("global_load_dwordx4 %0, %1, off sc0 sc1" : "=v"(av[ks]) : "v"(p0));
      }
      asm volatile("s_waitcnt vmcnt(0)" ::: "memory");
      #pragma unroll
      for (int ks=0; ks<16; ks++) asm volatile("" : "+v"(av[ks]));
      #pragma unroll
      for (int ks=0; ks<16; ks++){
        #pragma unroll
        for (int g3=0; g3<3; g3++){
          bf16x8 bfv = *(const bf16x8*)(&Wl[g3*16 + l16][ks*32 + quad*8]);
          acc[g3] = __builtin_amdgcn_mfma_f32_16x16x32_bf16(av[ks], bfv, acc[g3], 0,0,0);
        }
      }
    }
    u16 hbv[4];
    #pragma unroll
    for (int r=0; r<4; r++){
      float rr = sigm_f(gr_[r] + acc[0][r] + bh_r);
      float zz = sigm_f(gz_[r] + acc[1][r] + bh_z);
      float nn = tanhf (gn_[r] + rr*(acc[2][r] + bh_n));
      float h = (1.f-zz)*nn + zz*hold[r];
      hold[r] = h;
      hbv[r] = f2us(h);
      hbuf[wv*16 + quad*4 + r][l16] = hbv[r];
    }
    __syncthreads();
    if (tid < 64){
      const int bl = tid>>1, half = tid&1;
      u16* dst = hx + ((long)t*4 + bg)*16384 + bl*512 + cs*16 + half*8;
      u32x4 val = *(const u32x4*)(&hbuf[bl][half*8]);
      asm volatile("global_store_dwordx4 %0, %1, off sc0 sc1" :: "v"(dst), "v"(val) : "memory");
    }
    asm volatile("s_waitcnt vmcnt(0)" ::: "memory");   // h stores at LLC
    __syncthreads();
    if (tid==0){
      u32 tv = (u32)(t+1);
      const u32* fp = bar + c*4;
      asm volatile("global_store_dword %0, %1, off sc0 sc1" :: "v"(fp), "v"(tv) : "memory");
    }
    // off-critical-path row-major hs for the head GEMM
    #pragma unroll
    for (int r=0; r<4; r++){
      const int b = bg*32 + wv*16 + quad*4 + r;
      hs[((long)(t*128 + b))*512 + j] = hbv[r];
    }
  }
}

// ---------------------------------------------------------------- host
extern "C" void kernel_launch(void* const* d_in, const int* in_sizes, int n_in,
                              void* d_out, int out_size, void* d_ws, size_t ws_size,
                              hipStream_t stream){
  (void)in_sizes; (void)n_in; (void)out_size;
  const float* map_vec = (const float*)d_in[0];
  const int*   tm      = (const int*)  d_in[1];
  const float* mv_w  = (const float*)d_in[2];
  const float* mv_b  = (const float*)d_in[3];
  const float* te    = (const float*)d_in[4];
  const float* row_e = (const float*)d_in[5];
  const float* col_e = (const float*)d_in[6];
  const float* pos_w = (const float*)d_in[7];
  const float* pos_b = (const float*)d_in[8];
  const float* c1_w  = (const float*)d_in[9];
  const float* c1_b  = (const float*)d_in[10];
  const float* bn1_g = (const float*)d_in[11];
  const float* bn1_b = (const float*)d_in[12];
  const float* c2_w  = (const float*)d_in[13];
  const float* c2_b  = (const float*)d_in[14];
  const float* bn2_g = (const float*)d_in[15];
  const float* bn2_b = (const float*)d_in[16];
  const float* pf_w  = (const float*)d_in[17];
  const float* pf_b  = (const float*)d_in[18];
  const float* qkv_w = (const float*)d_in[19];
  const float* qkv_b = (const float*)d_in[20];
  const float* out_w = (const float*)d_in[21];
  const float* out_b = (const float*)d_in[22];
  const float* ln1_g = (const float*)d_in[23];
  const float* ln1_b = (const float*)d_in[24];
  const float* ff1_w = (const float*)d_in[25];
  const float* ff1_b = (const float*)d_in[26];
  const float* ff2_w = (const float*)d_in[27];
  const float* ff2_b = (const float*)d_in[28];
  const float* ln2_g = (const float*)d_in[29];
  const float* ln2_b = (const float*)d_in[30];
  const float* g_wih = (const float*)d_in[31];
  const float* g_whh = (const float*)d_in[32];
  const float* g_bih = (const float*)d_in[33];
  const float* g_bhh = (const float*)d_in[34];
  const float* fc1_w = (const float*)d_in[35];
  const float* fc1_b = (const float*)d_in[36];
  const float* fln_g = (const float*)d_in[37];
  const float* fln_b = (const float*)d_in[38];
  const float* fc2_w = (const float*)d_in[39];
  const float* fc2_b = (const float*)d_in[40];

  char* ws = (char*)d_ws;
  constexpr size_t O_BAR  = 0;                         // 2KB: 128 flags @16B
  constexpr size_t O_QKVW = 2048;
  constexpr size_t O_OUTW = O_QKVW + 1179648;
  constexpr size_t O_FF1W = O_OUTW + 393216;
  constexpr size_t O_FF2W = O_FF1W + 393216;
  constexpr size_t O_WIHW = O_FF2W + 393216;
  constexpr size_t O_FC1W = O_WIHW + 786432;
  constexpr size_t O_PFW  = O_FC1W + 524288;
  constexpr size_t O_W2K  = O_PFW  + 589824;
  constexpr size_t O_FC2W = O_W2K  + 147456;
  constexpr size_t O_FC2B = O_FC2W + 65536;
  constexpr size_t O_W1T  = O_FC2B + 256;
  constexpr size_t O_T2   = O_W1T  + 73728;
  constexpr size_t O_S2   = O_T2   + 1081600;
  constexpr size_t O_MV   = O_S2   + 512;
  constexpr size_t O_POS  = O_MV   + 131072;
  constexpr size_t O_ECLS = O_POS  + 173056;
  constexpr size_t O_R0   = ((O_ECLS + 540800 + 255)/256)*256;
  constexpr size_t R0_SZ  = 44302336;
  constexpr size_t O_R1   = O_R0 + R0_SZ;
  constexpr size_t R1_SZ  = 44302336;
  constexpr size_t O_R2   = O_R1 + R1_SZ;
  constexpr size_t R2_SZ  = 33226752;
  constexpr size_t ARENA_END = O_R2 + R2_SZ;
  if (ws_size < ARENA_END) return;
  const size_t O_HB    = O_R0;
  const size_t O_HX    = O_R0;
  const size_t O_HS    = O_R0 + 22151168;
  const size_t O_C1OUT = O_R1;
  const size_t O_OBUF  = O_R1;
  const size_t O_GIZ   = O_R1;
  const size_t O_Y1    = O_R1;
  const size_t O_YB    = O_R1 + 22151168;
  const size_t O_C2OUT = O_R2;
  const size_t O_QKVC  = O_R2;

  PrepArgs pa;
  pa.qkv_w=qkv_w; pa.out_w=out_w; pa.ff1_w=ff1_w; pa.ff2_w=ff2_w; pa.g_wih=g_wih;
  pa.fc1_w=fc1_w; pa.pf_w=pf_w; pa.c2_w=c2_w; pa.fc2_w=fc2_w; pa.fc2_b=fc2_b;
  pa.c1_w=c1_w; pa.c1_b=c1_b; pa.bn2_g=bn2_g;
  pa.map_vec=map_vec; pa.mv_w=mv_w; pa.mv_b=mv_b; pa.row_e=row_e; pa.col_e=col_e;
  pa.pos_w=pos_w; pa.pos_b=pos_b; pa.tm=tm;
  pa.qkvw_d=(u16*)(ws+O_QKVW); pa.outw_d=(u16*)(ws+O_OUTW); pa.ff1w_d=(u16*)(ws+O_FF1W);
  pa.ff2w_d=(u16*)(ws+O_FF2W); pa.wihw_d=(u16*)(ws+O_WIHW); pa.fc1w_d=(u16*)(ws+O_FC1W);
  pa.pfw_d=(u16*)(ws+O_PFW); pa.w2k_d=(u16*)(ws+O_W2K); pa.fc2w_d=(u16*)(ws+O_FC2W);
  pa.fc2b_d=(float*)(ws+O_FC2B); pa.w1t_d=(float*)(ws+O_W1T); pa.t2_d=(float*)(ws+O_T2);
  pa.s2_d=(float*)(ws+O_S2); pa.mv_d=(float*)(ws+O_MV); pa.pos_d=(float*)(ws+O_POS);
  pa.ecls_d=(u8*)(ws+O_ECLS); pa.bar=(unsigned*)(ws+O_BAR);
  prep_kernel<<<PREP_GRID, 256, 0, stream>>>(pa);

  token_kernel<<<21632, 256, 0, stream>>>(tm, te, (const float*)(ws+O_MV), (const float*)(ws+O_POS),
      (u16*)(ws+O_HB));

  for (int cc = 0; cc < 2; cc++){
    const int nbase = cc*10816;
    conv1_kernel<<<338, 256, 0, stream>>>((const u8*)(ws+O_ECLS), (const float*)(ws+O_W1T),
        (const float*)(ws+O_T2), bn1_g, bn1_b, (u16*)(ws+O_C1OUT), nbase);
    gemm_conv2<<<dim3(2,1521), 256, 0, stream>>>((const u16*)(ws+O_C1OUT), (const u16*)(ws+O_W2K),
        c2_b, (const float*)(ws+O_S2), bn2_b, (u16*)(ws+O_C2OUT));
    gemm_bt<4,0><<<dim3(1,169), 256, 0, stream>>>((const u16*)(ws+O_C2OUT), 1152, (const u16*)(ws+O_PFW),
        pf_b, nullptr, (u16*)(ws+O_HB) + (size_t)nbase*1024 + 768, 1024, 256, 1152, 0,
        nullptr, nullptr, nullptr);
  }

  for (int l=0; l<3; l++){
    for (int cc = 0; cc < 4; cc++){
      gemm_bt<4,0><<<dim3(3,338), 256, 0, stream>>>((const u16*)(ws+O_HB) + (size_t)cc*21632*256, 256,
          (const u16*)(ws+O_QKVW) + (size_t)l*768*256, qkv_b + l*768,
          nullptr, (u16*)(ws+O_QKVC), 768, 768, 256, 0, nullptr, nullptr, nullptr);
      attn_kernel<<<1352, 256, 0, stream>>>((const u16*)(ws+O_QKVC),
          (u16*)(ws+O_OBUF) + (size_t)cc*5408*4*256);
    }
    gemm_bt<4,2><<<dim3(1,1352), 256, 0, stream>>>((const u16*)(ws+O_OBUF), 256,
        (const u16*)(ws+O_OUTW) + (size_t)l*256*256, out_b + l*256,
        nullptr, (u16*)(ws+O_HB), 256, 256, 256, 0,
        (const u16*)(ws+O_HB), ln1_g + l*256, ln1_b + l*256);
    gemm_bt<4,0><<<dim3(1,1352), 256, 0, stream>>>((const u16*)(ws+O_HB), 256,
        (const u16*)(ws+O_FF1W) + (size_t)l*256*256, ff1_b + l*256,
        nullptr, (u16*)(ws+O_OBUF), 256, 256, 256, 1, nullptr, nullptr, nullptr);
    gemm_bt<4,2><<<dim3(1,1352), 256, 0, stream>>>((const u16*)(ws+O_OBUF), 256,
        (const u16*)(ws+O_FF2W) + (size_t)l*256*256, ff2_b + l*256,
        nullptr, (u16*)(ws+O_HB), 256, 256, 256, 0,
        (const u16*)(ws+O_HB), ln2_g + l*256, ln2_b + l*256);
  }

  // GRU input projection -> giZ (OM=1)
  gemm_bt<4,1><<<dim3(6,338), 256, 0, stream>>>((const u16*)(ws+O_HB), 1024, (const u16*)(ws+O_WIHW),
      g_bih, nullptr, (u16*)(ws+O_GIZ), 1536, 1536, 256, 0, nullptr, nullptr, nullptr);
  gru_kernel<<<128, 128, 0, stream>>>((const u16*)(ws+O_GIZ), g_whh, g_bhh,
      (u16*)(ws+O_HX), (u16*)(ws+O_HS), (unsigned*)(ws+O_BAR));

  // head (rows m = t*128+b)
  gemm_bt<4,0><<<dim3(2,338), 256, 0, stream>>>((const u16*)(ws+O_HS), 512, (const u16*)(ws+O_FC1W),
      fc1_b, nullptr, (u16*)(ws+O_Y1), 512, 512, 512, 0, nullptr, nullptr, nullptr);
  ln_kernel<8><<<5408, 256, 0, stream>>>((const u16*)(ws+O_Y1), nullptr, fln_g, fln_b,
      (u16*)(ws+O_YB), 1);
  gemm_bt<1,3><<<dim3(1,338), 256, 0, stream>>>((const u16*)(ws+O_YB), 512, (const u16*)(ws+O_FC2W),
      (const float*)(ws+O_FC2B), (float*)d_out, nullptr, 64, 64, 512, 0, nullptr, nullptr, nullptr);
}

// Round 14
// 2573.520 us; speedup vs baseline: 1.3076x; 1.1216x over previous
//
#include <hip/hip_runtime.h>
#include <hip/hip_bf16.h>

typedef unsigned short u16;
typedef unsigned char u8;
typedef unsigned int u32;
typedef __attribute__((ext_vector_type(8))) short bf16x8;
typedef __attribute__((ext_vector_type(4))) float f32x4;
typedef __attribute__((ext_vector_type(4))) unsigned int u32x4;

__device__ __forceinline__ float us2f(u16 u){ return __uint_as_float(((unsigned)u)<<16); }
__device__ __forceinline__ u16 f2us(float f){
  __hip_bfloat16 h = __float2bfloat16(f);
  union { __hip_bfloat16 b; u16 s; } cv; cv.b = h; return cv.s;
}
__device__ __forceinline__ float gelu_f(float v){ return 0.5f*v*(1.f+erff(v*0.70710678118654752f)); }
__device__ __forceinline__ float sigm_f(float v){ return 1.f/(1.f+expf(-v)); }
// async global->LDS, 16B per lane; LDS dest = uniform base + lane*16 (CK-style casts)
__device__ __forceinline__ void gld_lds16(const u16* g, u16* l){
  __builtin_amdgcn_global_load_lds(
      (const __attribute__((address_space(1))) u32*)g,
      (__attribute__((address_space(3))) u32*)(u32)(unsigned long long)l,
      16, 0, 0);
}

#define BNSC 0.9999950000374997f  /* 1/sqrt(1+1e-5) */

// ---------------------------------------------------------------- fused prep
struct PrepArgs {
  const float *qkv_w, *out_w, *ff1_w, *ff2_w, *g_wih, *fc1_w, *pf_w, *c2_w, *fc2_w, *fc2_b;
  const float *c1_w, *c1_b, *bn2_g;
  const float *map_vec, *mv_w, *mv_b, *row_e, *col_e, *pos_w, *pos_b;
  const int *tm;
  u16 *qkvw_d, *outw_d, *ff1w_d, *ff2w_d, *wihw_d, *fc1w_d, *pfw_d, *w2k_d, *fc2w_d;
  float *fc2b_d, *w1t_d, *t2_d, *s2_d, *mv_d, *pos_d;
  u8 *ecls_d;
  unsigned *bar;
};
#define SB_QKV 2304
#define SB_O   768
#define SB_WIH 1536
#define SB_FC1 1024
#define SB_PF  1152
#define SB_W2  288
#define SB_FC2 128
#define SB_W1T 72
#define SB_T2  1057
#define SB_MV  128
#define SB_POS 169
#define SB_EC  2113
#define PREP_GRID (1+SB_QKV+3*SB_O+SB_WIH+SB_FC1+SB_PF+SB_W2+SB_FC2+SB_W1T+SB_T2+SB_MV+SB_POS+SB_EC)

__global__ __launch_bounds__(256) void prep_kernel(PrepArgs a){
  int bb = blockIdx.x; const int tid = threadIdx.x;
  if (bb < 1){
    a.bar[tid] = 0u; a.bar[256+tid] = 0u;       // 2KB flag region (128 flags @16B)
    if (tid < 128) a.s2_d[tid] = a.bn2_g[tid]*BNSC;
    return;
  } bb -= 1;
  if (bb < SB_QKV){ int i = bb*256+tid; a.qkvw_d[i] = f2us(a.qkv_w[i]); return; } bb -= SB_QKV;
  if (bb < SB_O){ int i = bb*256+tid; a.outw_d[i] = f2us(a.out_w[i]); return; } bb -= SB_O;
  if (bb < SB_O){ int i = bb*256+tid; a.ff1w_d[i] = f2us(a.ff1_w[i]); return; } bb -= SB_O;
  if (bb < SB_O){ int i = bb*256+tid; a.ff2w_d[i] = f2us(a.ff2_w[i]); return; } bb -= SB_O;
  if (bb < SB_WIH){ int i = bb*256+tid; a.wihw_d[i] = f2us(a.g_wih[i]); return; } bb -= SB_WIH;
  if (bb < SB_FC1){ int i = bb*256+tid; a.fc1w_d[i] = f2us(a.fc1_w[i]); return; } bb -= SB_FC1;
  if (bb < SB_PF){
    int i = bb*256+tid;
    int o = i/1152, kp = i%1152, pos = kp>>7, c = kp&127;
    a.pfw_d[i] = f2us(a.pf_w[o*1152 + c*9 + pos]); return;
  } bb -= SB_PF;
  if (bb < SB_W2){
    int i = bb*256+tid;
    int o = i/576, k = i%576, tap = k>>6, ic = k&63, ty = tap/3, tx = tap%3;
    a.w2k_d[i] = f2us(a.c2_w[((o*64 + ic)*3 + ty)*3 + tx]); return;
  } bb -= SB_W2;
  if (bb < SB_FC2){
    int i = bb*256+tid;
    int o = i>>9, k = i&511;
    a.fc2w_d[i] = (o<32) ? f2us(a.fc2_w[o*512+k]) : (u16)0;
    if (i < 64) a.fc2b_d[i] = (i<32) ? a.fc2_b[i] : 0.f;
    return;
  } bb -= SB_FC2;
  if (bb < SB_W1T){
    int i = bb*256+tid;
    int c = i/576, r = i%576, tap = r>>6, o = r&63;
    a.w1t_d[i] = a.c1_w[(o*33 + c)*9 + tap]; return;
  } bb -= SB_W1T;
  if (bb < SB_T2){
    int i = bb*256+tid; if (i >= 169*25*64) return;
    int blk = i/64, o = i%64;
    int p = blk/25, op = blk%25, oy = op/5, ox = op%5;
    int yp = p/13, xp = p%13;
    float acc = a.c1_b[o];
    for (int dy=0; dy<3; dy++) for (int dx=0; dx<3; dx++){
      int Y = oy+dy-1, X = ox+dx-1;
      if (Y<0||Y>4||X<0||X>4) continue;
      int rr = yp + Y - 4, cc = xp + X - 2;
      bool m = (rr>=0) && (cc>=0) && (cc<13) && !(Y==4 && X>=2);
      if (m) acc += a.c1_w[(o*33 + 32)*9 + dy*3 + dx];
    }
    a.t2_d[((long)p*25 + op)*64 + o] = acc; return;
  } bb -= SB_T2;
  if (bb < SB_MV){
    int i = bb*256+tid;
    int bi = i>>8, o = i&255;
    float acc = a.mv_b[o];
    for (int k=0;k<32;k++) acc += a.map_vec[bi*32+k]*a.mv_w[o*32+k];
    a.mv_d[i] = acc; return;
  } bb -= SB_MV;
  if (bb < SB_POS){
    int i = bb*256+tid;
    int p = i>>8, o = i&255;
    int y = p/13, x = p%13;
    const float* wr = a.pos_w + o*512;
    float acc = a.pos_b[o];
    for (int k=0;k<256;k++) acc += a.row_e[y*256+k]*wr[k];
    for (int k=0;k<256;k++) acc += a.col_e[x*256+k]*wr[256+k];
    a.pos_d[i] = acc; return;
  } bb -= SB_POS;
  {
    int id = bb*256+tid; if (id >= 21632*25) return;
    int n = id/25, q = id%25, Y = q/5, X = q%5;
    int b = n/169, p = n%169, yp = p/13, xp = p%13;
    int rr = yp + X - 4, cc = xp + Y - 2;
    int val = 0;
    if (rr>=0 && cc>=0 && cc<13 && !(X==4 && Y>=2)) val = a.tm[b*169 + rr*13 + cc];
    a.ecls_d[id] = (u8)val;
  }
}

// conv1 gather + BN + gelu
__global__ __launch_bounds__(256) void conv1_kernel(
    const u8* __restrict__ ec, const float* __restrict__ w1t, const float* __restrict__ t2,
    const float* __restrict__ bn1g, const float* __restrict__ bn1b, u16* __restrict__ c1out,
    int nbase){
  __shared__ __align__(16) u16 w1s[32*9*64];
  __shared__ u8 ecs[32*25];
  const int tid = threadIdx.x, nl0 = blockIdx.x*32;
  for (int i=tid; i<32*9*64; i+=256) w1s[i] = f2us(w1t[i]);
  for (int i=tid; i<32*25;   i+=256) ecs[i] = ec[((long)nbase + nl0)*25 + i];
  __syncthreads();
  const int grp = tid>>6, o = tid&63;
  const float s1 = bn1g[o]*BNSC, t1 = bn1b[o];
  for (int it = grp; it < 800; it += 4){
    const int nl = it/25, op = it%25, oy = op/5, ox = op%5;
    const int n = nbase + nl0 + nl, p = n%169;
    float acc = t2[((long)p*25 + op)*64 + o];
    #pragma unroll
    for (int dy=0; dy<3; dy++)
      #pragma unroll
      for (int dx=0; dx<3; dx++){
        int Y = oy+dy-1, X = ox+dx-1;
        if (Y>=0 && Y<5 && X>=0 && X<5){
          int e = ecs[nl*25 + Y*5 + X];
          acc += us2f(w1s[(e*9 + dy*3+dx)*64 + o]);
        }
      }
    c1out[((long)(nl0+nl)*25 + op)*64 + o] = f2us(gelu_f(acc*s1 + t1));
  }
}

// ----------------------------------------------- BM=64 GEMM C = A@W^T
// v2 staging: async global_load_lds (16B/lane) into UNPADDED LDS with XOR chunk
// swizzle on the global side; frag reads un-swizzle. 40KB LDS @NT=4 -> 4 blocks/CU.
// OM 0: row-major out (in-place safe when grid.x==1)
// OM 1: giZ scatter [t][bg4][cs32][g3][jl16][bl32], m=b*169+t
// OM 2: LN epilogue (grid.x==1, N==64*NT): outB = LN(acc+bias+lbase)*lg+lb
// OM 3: head scatter: m=t*128+b2, n<32 -> outF[(b2*32+n)*169+t]
template<int NT, int OM>
__global__ __launch_bounds__(256) void gemm_bt(
    const u16* A, long lda, const u16* __restrict__ W,
    const float* __restrict__ bias,
    float* outF, u16* outB, long ldc, int N, int K, int act,
    const u16* __restrict__ lbase, const float* __restrict__ lg, const float* __restrict__ lb){
  __shared__ __align__(16) u16 As[64*64];
  __shared__ __align__(16) u16 Ws[NT*64*64];
  const int tid = threadIdx.x, wv = tid>>6, lane = tid&63;
  const int quad = lane>>4, l16 = lane&15;
  const int bm = blockIdx.y, bn = blockIdx.x;
  const int lrow = lane>>3, lchk = lane&7;
  f32x4 acc[NT*4];
  #pragma unroll
  for (int i=0;i<NT*4;i++) acc[i] = (f32x4){0.f,0.f,0.f,0.f};
  // per-call global base pointers (advance by 64 per kb); LDS bases are fixed
  const u16* agp[2]; u16* alp[2];
  #pragma unroll
  for (int c=0;c<2;c++){
    const int row = c*32 + wv*8 + lrow;
    const int cg = lchk ^ (row & 7);
    agp[c] = A + (long)(bm*64 + row)*lda + cg*8;
    alp[c] = As + (c*32 + wv*8)*64;
  }
  const u16* wgp[2*NT]; u16* wlp[2*NT];
  #pragma unroll
  for (int j=0;j<2*NT;j++){
    const int nrow = j*32 + wv*8 + lrow;
    const int cg = lchk ^ (nrow & 7);
    wgp[j] = W + (long)(bn*(64*NT) + nrow)*K + cg*8;
    wlp[j] = Ws + (j*32 + wv*8)*64;
  }
  for (int kb = 0; kb < K; kb += 64){
    #pragma unroll
    for (int c=0;c<2;c++){ gld_lds16(agp[c], alp[c]); agp[c] += 64; }
    #pragma unroll
    for (int j=0;j<2*NT;j++){ gld_lds16(wgp[j], wlp[j]); wgp[j] += 64; }
    asm volatile("s_waitcnt vmcnt(0)" ::: "memory");
    __syncthreads();
    #pragma unroll
    for (int ks = 0; ks < 64; ks += 32){
      const int cq = (ks>>3) + quad;
      const int arow = wv*16 + l16;
      bf16x8 af = *(const bf16x8*)&As[arow*64 + ((cq ^ (arow&7))<<3)];
      #pragma unroll
      for (int wt=0; wt<NT; wt++)
        #pragma unroll
        for (int s=0; s<4; s++){
          const int nr = wt*64 + s*16 + l16;
          bf16x8 bfv = *(const bf16x8*)&Ws[nr*64 + ((cq ^ (nr&7))<<3)];
          acc[wt*4+s] = __builtin_amdgcn_mfma_f32_16x16x32_bf16(af, bfv, acc[wt*4+s], 0, 0, 0);
        }
    }
    __syncthreads();
  }
  const int mb = bm*64 + wv*16 + quad*4;
  if (OM == 2){
    #pragma unroll
    for (int wt=0; wt<NT; wt++)
      #pragma unroll
      for (int s=0; s<4; s++){
        const int n = wt*64 + s*16 + l16;
        const float bv = bias[n];
        #pragma unroll
        for (int r=0;r<4;r++)
          acc[wt*4+s][r] = acc[wt*4+s][r] + bv + us2f(lbase[(long)(mb+r)*N + n]);
      }
    float mean[4], rstd[4];
    #pragma unroll
    for (int r=0;r<4;r++){
      float s = 0.f;
      #pragma unroll
      for (int i=0;i<NT*4;i++) s += acc[i][r];
      s += __shfl_xor(s,1); s += __shfl_xor(s,2); s += __shfl_xor(s,4); s += __shfl_xor(s,8);
      mean[r] = s / N;
      float v = 0.f;
      #pragma unroll
      for (int i=0;i<NT*4;i++){ float d = acc[i][r]-mean[r]; v += d*d; }
      v += __shfl_xor(v,1); v += __shfl_xor(v,2); v += __shfl_xor(v,4); v += __shfl_xor(v,8);
      rstd[r] = rsqrtf(v/N + 1e-5f);
    }
    #pragma unroll
    for (int wt=0; wt<NT; wt++)
      #pragma unroll
      for (int s=0; s<4; s++){
        const int n = wt*64 + s*16 + l16;
        const float gv = lg[n], bvv = lb[n];
        #pragma unroll
        for (int r=0;r<4;r++)
          outB[(long)(mb+r)*ldc + n] = f2us((acc[wt*4+s][r]-mean[r])*rstd[r]*gv + bvv);
      }
    return;
  }
  #pragma unroll
  for (int wt=0; wt<NT; wt++)
    #pragma unroll
    for (int s=0; s<4; s++){
      const int n = bn*(64*NT) + wt*64 + s*16 + l16;
      const float bv = bias ? bias[n] : 0.f;
      #pragma unroll
      for (int r=0;r<4;r++){
        float v = acc[wt*4+s][r] + bv;
        if (act==1) v = fmaxf(v, 0.f);
        else if (act==2) v = gelu_f(v);
        if (OM == 1){
          const int m = mb + r, b = m/169, tt = m%169;
          const int g = n>>9, j = n&511, cs = j>>4, jl = j&15, bg = b>>5, bl = b&31;
          outB[((((long)tt*4 + bg)*32 + cs)*48 + g*16 + jl)*32 + bl] = f2us(v);
        } else if (OM == 3){
          if (n < 32){
            const int m = mb + r, t = m/128, b2 = m%128;
            outF[((long)b2*32 + n)*169 + t] = v;
          }
        } else {
          const long oo = (long)(mb + r)*ldc + n;
          if (outF) outF[oo] = v;
          if (outB) outB[oo] = f2us(v);
        }
      }
    }
}

// conv2 implicit-im2col GEMM (unchanged, R12-proven)
__global__ __launch_bounds__(256) void gemm_conv2(
    const u16* __restrict__ C1, const u16* __restrict__ W,
    const float* __restrict__ bias, const float* __restrict__ scale, const float* __restrict__ shift,
    u16* __restrict__ outB){
  __shared__ __align__(16) u16 As[64][72];
  __shared__ __align__(16) u16 Ws[64][72];
  const int tid = threadIdx.x, wv = tid>>6, lane = tid&63;
  const int quad = lane>>4, l16 = lane&15;
  const int bm = blockIdx.y, bn = blockIdx.x;
  f32x4 acc[4];
  #pragma unroll
  for (int i=0;i<4;i++) acc[i] = (f32x4){0.f,0.f,0.f,0.f};
  const int sm = tid>>2, sk = (tid&3)<<4;
  const int g = bm*64 + sm, n_ = g/9, pos = g%9, py = pos/3, px = pos%3;
  const long wrow = (long)(bn*64 + sm)*576;
  for (int tap = 0; tap < 9; tap++){
    const int kb = tap*64;
    const long aoff = ((long)n_*25 + (py + tap/3)*5 + (px + tap%3))*64 + sk;
    int4 a0 = *(const int4*)(C1 + aoff);
    int4 a1 = *(const int4*)(C1 + aoff + 8);
    int4 w0 = *(const int4*)(W + wrow + kb + sk);
    int4 w1 = *(const int4*)(W + wrow + kb + sk + 8);
    *(int4*)&As[sm][sk]   = a0;  *(int4*)&As[sm][sk+8] = a1;
    *(int4*)&Ws[sm][sk]   = w0;  *(int4*)&Ws[sm][sk+8] = w1;
    __syncthreads();
    #pragma unroll
    for (int ks = 0; ks < 64; ks += 32){
      bf16x8 af = *(const bf16x8*)(&As[wv*16 + l16][ks + quad*8]);
      #pragma unroll
      for (int nt=0; nt<4; nt++){
        bf16x8 bfv = *(const bf16x8*)(&Ws[nt*16 + l16][ks + quad*8]);
        acc[nt] = __builtin_amdgcn_mfma_f32_16x16x32_bf16(af, bfv, acc[nt], 0, 0, 0);
      }
    }
    __syncthreads();
  }
  const int mb = bm*64 + wv*16 + quad*4;
  #pragma unroll
  for (int nt=0; nt<4; nt++){
    const int n = bn*64 + nt*16 + l16;
    const float bv = bias[n], sc = scale[n], sh = shift[n];
    #pragma unroll
    for (int r=0;r<4;r++){
      float v = (acc[nt][r] + bv)*sc + sh;
      outB[(long)(mb + r)*128 + n] = f2us(gelu_f(v));
    }
  }
}

// tokens -> h bf16 [86528][256]; fills slots 0..2
__global__ void token_kernel(const int* __restrict__ tm, const float* __restrict__ te,
                             const float* __restrict__ mv, const float* __restrict__ pos,
                             u16* __restrict__ hB){
  const int n = blockIdx.x, k = threadIdx.x;
  const int b = n/169, p = n%169;
  const int prev = (p==0) ? 31 : tm[b*169 + p - 1];
  const long r0 = (long)n*1024;
  hB[r0 + k]        = f2us(te[prev*256 + k]);
  hB[r0 + 256 + k]  = f2us(mv[b*256 + k]);
  hB[r0 + 512 + k]  = f2us(pos[p*256 + k]);
}

// attention
__global__ __launch_bounds__(256) void attn_kernel(const u16* __restrict__ qkv, u16* o){
  const int n = blockIdx.x*4 + (threadIdx.x>>6);
  const int lane = threadIdx.x & 63;
  float qv[4][2][2], kv[4][2][2], vv[4][2][2];
  #pragma unroll
  for (int tok=0; tok<4; tok++){
    const long rb = (long)(n*4+tok)*768;
    #pragma unroll
    for (int h=0; h<2; h++){
      unsigned u;
      u = *(const unsigned*)(qkv + rb +        h*128 + 2*lane); qv[tok][h][0]=us2f(u&0xffff); qv[tok][h][1]=us2f(u>>16);
      u = *(const unsigned*)(qkv + rb + 256 +  h*128 + 2*lane); kv[tok][h][0]=us2f(u&0xffff); kv[tok][h][1]=us2f(u>>16);
      u = *(const unsigned*)(qkv + rb + 512 +  h*128 + 2*lane); vv[tok][h][0]=us2f(u&0xffff); vv[tok][h][1]=us2f(u>>16);
    }
  }
  float sc[2][4][4];
  #pragma unroll
  for (int h=0; h<2; h++)
    #pragma unroll
    for (int qt=0; qt<4; qt++)
      #pragma unroll
      for (int kt=0; kt<4; kt++){
        float p_ = qv[qt][h][0]*kv[kt][h][0] + qv[qt][h][1]*kv[kt][h][1];
        for (int off=32; off; off>>=1) p_ += __shfl_xor(p_, off);
        sc[h][qt][kt] = p_ * 0.08838834764831845f;
      }
  #pragma unroll
  for (int h=0; h<2; h++)
    #pragma unroll
    for (int qt=0; qt<4; qt++){
      float m = fmaxf(fmaxf(sc[h][qt][0],sc[h][qt][1]),fmaxf(sc[h][qt][2],sc[h][qt][3]));
      float s = 0.f;
      #pragma unroll
      for (int kt=0; kt<4; kt++){ sc[h][qt][kt] = expf(sc[h][qt][kt]-m); s += sc[h][qt][kt]; }
      float inv = 1.f/s;
      #pragma unroll
      for (int kt=0; kt<4; kt++) sc[h][qt][kt] *= inv;
    }
  #pragma unroll
  for (int qt=0; qt<4; qt++)
    #pragma unroll
    for (int h=0; h<2; h++){
      float o0=0.f, o1=0.f;
      #pragma unroll
      for (int kt=0; kt<4; kt++){ o0 += sc[h][qt][kt]*vv[kt][h][0]; o1 += sc[h][qt][kt]*vv[kt][h][1]; }
      unsigned u = (unsigned)f2us(o0) | ((unsigned)f2us(o1)<<16);
      *(unsigned*)(o + (long)(n*4+qt)*256 + h*128 + 2*lane) = u;
    }
}

// LayerNorm — head fcln(+gelu) only
template<int NPL>
__global__ __launch_bounds__(256) void ln_kernel(
    const u16* __restrict__ delta, const u16* __restrict__ base,
    const float* __restrict__ g, const float* __restrict__ b,
    u16* __restrict__ out, int do_gelu){
  const int D = NPL*64;
  const int row = blockIdx.x*4 + (threadIdx.x>>6);
  const int lane = threadIdx.x & 63;
  const long ro = (long)row*D;
  float x[NPL];
  float s = 0.f;
  #pragma unroll
  for (int i=0;i<NPL;i++){
    float v = us2f(delta[ro + i*64 + lane]);
    if (base) v += us2f(base[ro + i*64 + lane]);
    x[i] = v; s += v;
  }
  for (int off=32; off; off>>=1) s += __shfl_xor(s, off);
  const float mean = s / D;
  float var = 0.f;
  #pragma unroll
  for (int i=0;i<NPL;i++){ float dd = x[i]-mean; var += dd*dd; }
  for (int off=32; off; off>>=1) var += __shfl_xor(var, off);
  const float rs = rsqrtf(var/D + 1e-5f);
  #pragma unroll
  for (int i=0;i<NPL;i++){
    float y = (x[i]-mean)*rs*g[i*64+lane] + b[i*64+lane];
    if (do_gelu) y = gelu_f(y);
    out[ro + i*64 + lane] = f2us(y);
  }
}

// GRU v8 (R13-proven): 128 WGs x 128 thr, per-batch-group sync, wide sc0/sc1 exchange.
__global__ __launch_bounds__(128) void gru_kernel(
    const u16* __restrict__ giz, const float* __restrict__ whh,
    const float* __restrict__ bhh, u16* __restrict__ hx, u16* __restrict__ hs,
    unsigned* __restrict__ bar){
  __shared__ __align__(16) u16 Wl[48][520];
  __shared__ __align__(16) u16 hbuf[32][16];
  const int c = blockIdx.x, tid = threadIdx.x;
  const int bg = c>>5, cs = c&31;
  const int wv = tid>>6, lane = tid&63, quad = lane>>4, l16 = lane&15;
  for (int idx = tid; idx < 48*512; idx += 128){
    int rr = idx >> 9, k = idx & 511;
    int gate = rr >> 4, jl = rr & 15;
    Wl[rr][k] = f2us(whh[((gate<<9) + (cs<<4) + jl)*512 + k]);
  }
  const int j = (cs<<4) + l16;
  const float bh_r = bhh[j], bh_z = bhh[512+j], bh_n = bhh[1024+j];
  __syncthreads();
  float hold[4] = {0.f,0.f,0.f,0.f};
  for (int t=0; t<169; t++){
    const u16* gbase = giz + (((long)t*4 + bg)*32 + cs)*1536;
    float gr_[4], gz_[4], gn_[4];
    #pragma unroll
    for (int r=0; r<4; r++){
      const int bl = wv*16 + quad*4 + r;
      gr_[r] = us2f(gbase[(0*16 + l16)*32 + bl]);
      gz_[r] = us2f(gbase[(1*16 + l16)*32 + bl]);
      gn_[r] = us2f(gbase[(2*16 + l16)*32 + bl]);
    }
    if (t>0){
      if (tid < 32){
        const u32* fp = bar + (bg*32 + tid)*4;
        u32 v;
        do {
          asm volatile("global_load_dword %0, %1, off sc0 sc1" : "=v"(v) : "v"(fp));
          asm volatile("s_waitcnt vmcnt(0)" ::: "memory");
        } while ((int)v < t);
      }
      __syncthreads();
    }
    f32x4 acc[3];
    #pragma unroll
    for (int g3=0; g3<3; g3++) acc[g3] = (f32x4){0.f,0.f,0.f,0.f};
    if (t>0){
      const long tb = ((long)(t-1)*4 + bg)*16384;
      const int bl = wv*16 + l16;
      bf16x8 av[16];
      #pragma unroll
      for (int ks=0; ks<16; ks++){
        const u16* p0 = hx + tb + bl*512 + ks*32 + quad*8;
        asm volatile("global_load_dwordx4 %0, %1, off sc0 sc1" : "=v"(av[ks]) : "v"(p0));
      }
      asm volatile("s_waitcnt vmcnt(0)" ::: "memory");
      #pragma unroll
      for (int ks=0; ks<16; ks++) asm volatile("" : "+v"(av[ks]));
      #pragma unroll
      for (int ks=0; ks<16; ks++){
        #pragma unroll
        for (int g3=0; g3<3; g3++){
          bf16x8 bfv = *(const bf16x8*)(&Wl[g3*16 + l16][ks*32 + quad*8]);
          acc[g3] = __builtin_amdgcn_mfma_f32_16x16x32_bf16(av[ks], bfv, acc[g3], 0,0,0);
        }
      }
    }
    u16 hbv[4];
    #pragma unroll
    for (int r=0; r<4; r++){
      float rr = sigm_f(gr_[r] + acc[0][r] + bh_r);
      float zz = sigm_f(gz_[r] + acc[1][r] + bh_z);
      float nn = tanhf (gn_[r] + rr*(acc[2][r] + bh_n));
      float h = (1.f-zz)*nn + zz*hold[r];
      hold[r] = h;
      hbv[r] = f2us(h);
      hbuf[wv*16 + quad*4 + r][l16] = hbv[r];
    }
    __syncthreads();
    if (tid < 64){
      const int bl = tid>>1, half = tid&1;
      u16* dst = hx + ((long)t*4 + bg)*16384 + bl*512 + cs*16 + half*8;
      u32x4 val = *(const u32x4*)(&hbuf[bl][half*8]);
      asm volatile("global_store_dwordx4 %0, %1, off sc0 sc1" :: "v"(dst), "v"(val) : "memory");
    }
    asm volatile("s_waitcnt vmcnt(0)" ::: "memory");
    __syncthreads();
    if (tid==0){
      u32 tv = (u32)(t+1);
      const u32* fp = bar + c*4;
      asm volatile("global_store_dword %0, %1, off sc0 sc1" :: "v"(fp), "v"(tv) : "memory");
    }
    #pragma unroll
    for (int r=0; r<4; r++){
      const int b = bg*32 + wv*16 + quad*4 + r;
      hs[((long)(t*128 + b))*512 + j] = hbv[r];
    }
  }
}

// ---------------------------------------------------------------- host
extern "C" void kernel_launch(void* const* d_in, const int* in_sizes, int n_in,
                              void* d_out, int out_size, void* d_ws, size_t ws_size,
                              hipStream_t stream){
  (void)in_sizes; (void)n_in; (void)out_size;
  const float* map_vec = (const float*)d_in[0];
  const int*   tm      = (const int*)  d_in[1];
  const float* mv_w  = (const float*)d_in[2];
  const float* mv_b  = (const float*)d_in[3];
  const float* te    = (const float*)d_in[4];
  const float* row_e = (const float*)d_in[5];
  const float* col_e = (const float*)d_in[6];
  const float* pos_w = (const float*)d_in[7];
  const float* pos_b = (const float*)d_in[8];
  const float* c1_w  = (const float*)d_in[9];
  const float* c1_b  = (const float*)d_in[10];
  const float* bn1_g = (const float*)d_in[11];
  const float* bn1_b = (const float*)d_in[12];
  const float* c2_w  = (const float*)d_in[13];
  const float* c2_b  = (const float*)d_in[14];
  const float* bn2_g = (const float*)d_in[15];
  const float* bn2_b = (const float*)d_in[16];
  const float* pf_w  = (const float*)d_in[17];
  const float* pf_b  = (const float*)d_in[18];
  const float* qkv_w = (const float*)d_in[19];
  const float* qkv_b = (const float*)d_in[20];
  const float* out_w = (const float*)d_in[21];
  const float* out_b = (const float*)d_in[22];
  const float* ln1_g = (const float*)d_in[23];
  const float* ln1_b = (const float*)d_in[24];
  const float* ff1_w = (const float*)d_in[25];
  const float* ff1_b = (const float*)d_in[26];
  const float* ff2_w = (const float*)d_in[27];
  const float* ff2_b = (const float*)d_in[28];
  const float* ln2_g = (const float*)d_in[29];
  const float* ln2_b = (const float*)d_in[30];
  const float* g_wih = (const float*)d_in[31];
  const float* g_whh = (const float*)d_in[32];
  const float* g_bih = (const float*)d_in[33];
  const float* g_bhh = (const float*)d_in[34];
  const float* fc1_w = (const float*)d_in[35];
  const float* fc1_b = (const float*)d_in[36];
  const float* fln_g = (const float*)d_in[37];
  const float* fln_b = (const float*)d_in[38];
  const float* fc2_w = (const float*)d_in[39];
  const float* fc2_b = (const float*)d_in[40];

  char* ws = (char*)d_ws;
  constexpr size_t O_BAR  = 0;                         // 2KB: 128 flags @16B
  constexpr size_t O_QKVW = 2048;
  constexpr size_t O_OUTW = O_QKVW + 1179648;
  constexpr size_t O_FF1W = O_OUTW + 393216;
  constexpr size_t O_FF2W = O_FF1W + 393216;
  constexpr size_t O_WIHW = O_FF2W + 393216;
  constexpr size_t O_FC1W = O_WIHW + 786432;
  constexpr size_t O_PFW  = O_FC1W + 524288;
  constexpr size_t O_W2K  = O_PFW  + 589824;
  constexpr size_t O_FC2W = O_W2K  + 147456;
  constexpr size_t O_FC2B = O_FC2W + 65536;
  constexpr size_t O_W1T  = O_FC2B + 256;
  constexpr size_t O_T2   = O_W1T  + 73728;
  constexpr size_t O_S2   = O_T2   + 1081600;
  constexpr size_t O_MV   = O_S2   + 512;
  constexpr size_t O_POS  = O_MV   + 131072;
  constexpr size_t O_ECLS = O_POS  + 173056;
  constexpr size_t O_R0   = ((O_ECLS + 540800 + 255)/256)*256;
  constexpr size_t R0_SZ  = 44302336;
  constexpr size_t O_R1   = O_R0 + R0_SZ;
  constexpr size_t R1_SZ  = 44302336;
  constexpr size_t O_R2   = O_R1 + R1_SZ;
  constexpr size_t R2_SZ  = 33226752;
  constexpr size_t ARENA_END = O_R2 + R2_SZ;
  if (ws_size < ARENA_END) return;
  const size_t O_HB    = O_R0;
  const size_t O_HX    = O_R0;
  const size_t O_HS    = O_R0 + 22151168;
  const size_t O_C1OUT = O_R1;
  const size_t O_OBUF  = O_R1;
  const size_t O_GIZ   = O_R1;
  const size_t O_Y1    = O_R1;
  const size_t O_YB    = O_R1 + 22151168;
  const size_t O_C2OUT = O_R2;
  const size_t O_QKVC  = O_R2;

  PrepArgs pa;
  pa.qkv_w=qkv_w; pa.out_w=out_w; pa.ff1_w=ff1_w; pa.ff2_w=ff2_w; pa.g_wih=g_wih;
  pa.fc1_w=fc1_w; pa.pf_w=pf_w; pa.c2_w=c2_w; pa.fc2_w=fc2_w; pa.fc2_b=fc2_b;
  pa.c1_w=c1_w; pa.c1_b=c1_b; pa.bn2_g=bn2_g;
  pa.map_vec=map_vec; pa.mv_w=mv_w; pa.mv_b=mv_b; pa.row_e=row_e; pa.col_e=col_e;
  pa.pos_w=pos_w; pa.pos_b=pos_b; pa.tm=tm;
  pa.qkvw_d=(u16*)(ws+O_QKVW); pa.outw_d=(u16*)(ws+O_OUTW); pa.ff1w_d=(u16*)(ws+O_FF1W);
  pa.ff2w_d=(u16*)(ws+O_FF2W); pa.wihw_d=(u16*)(ws+O_WIHW); pa.fc1w_d=(u16*)(ws+O_FC1W);
  pa.pfw_d=(u16*)(ws+O_PFW); pa.w2k_d=(u16*)(ws+O_W2K); pa.fc2w_d=(u16*)(ws+O_FC2W);
  pa.fc2b_d=(float*)(ws+O_FC2B); pa.w1t_d=(float*)(ws+O_W1T); pa.t2_d=(float*)(ws+O_T2);
  pa.s2_d=(float*)(ws+O_S2); pa.mv_d=(float*)(ws+O_MV); pa.pos_d=(float*)(ws+O_POS);
  pa.ecls_d=(u8*)(ws+O_ECLS); pa.bar=(unsigned*)(ws+O_BAR);
  prep_kernel<<<PREP_GRID, 256, 0, stream>>>(pa);

  token_kernel<<<21632, 256, 0, stream>>>(tm, te, (const float*)(ws+O_MV), (const float*)(ws+O_POS),
      (u16*)(ws+O_HB));

  for (int cc = 0; cc < 2; cc++){
    const int nbase = cc*10816;
    conv1_kernel<<<338, 256, 0, stream>>>((const u8*)(ws+O_ECLS), (const float*)(ws+O_W1T),
        (const float*)(ws+O_T2), bn1_g, bn1_b, (u16*)(ws+O_C1OUT), nbase);
    gemm_conv2<<<dim3(2,1521), 256, 0, stream>>>((const u16*)(ws+O_C1OUT), (const u16*)(ws+O_W2K),
        c2_b, (const float*)(ws+O_S2), bn2_b, (u16*)(ws+O_C2OUT));
    gemm_bt<4,0><<<dim3(1,169), 256, 0, stream>>>((const u16*)(ws+O_C2OUT), 1152, (const u16*)(ws+O_PFW),
        pf_b, nullptr, (u16*)(ws+O_HB) + (size_t)nbase*1024 + 768, 1024, 256, 1152, 0,
        nullptr, nullptr, nullptr);
  }

  for (int l=0; l<3; l++){
    for (int cc = 0; cc < 4; cc++){
      gemm_bt<4,0><<<dim3(3,338), 256, 0, stream>>>((const u16*)(ws+O_HB) + (size_t)cc*21632*256, 256,
          (const u16*)(ws+O_QKVW) + (size_t)l*768*256, qkv_b + l*768,
          nullptr, (u16*)(ws+O_QKVC), 768, 768, 256, 0, nullptr, nullptr, nullptr);
      attn_kernel<<<1352, 256, 0, stream>>>((const u16*)(ws+O_QKVC),
          (u16*)(ws+O_OBUF) + (size_t)cc*5408*4*256);
    }
    gemm_bt<4,2><<<dim3(1,1352), 256, 0, stream>>>((const u16*)(ws+O_OBUF), 256,
        (const u16*)(ws+O_OUTW) + (size_t)l*256*256, out_b + l*256,
        nullptr, (u16*)(ws+O_HB), 256, 256, 256, 0,
        (const u16*)(ws+O_HB), ln1_g + l*256, ln1_b + l*256);
    gemm_bt<4,0><<<dim3(1,1352), 256, 0, stream>>>((const u16*)(ws+O_HB), 256,
        (const u16*)(ws+O_FF1W) + (size_t)l*256*256, ff1_b + l*256,
        nullptr, (u16*)(ws+O_OBUF), 256, 256, 256, 1, nullptr, nullptr, nullptr);
    gemm_bt<4,2><<<dim3(1,1352), 256, 0, stream>>>((const u16*)(ws+O_OBUF), 256,
        (const u16*)(ws+O_FF2W) + (size_t)l*256*256, ff2_b + l*256,
        nullptr, (u16*)(ws+O_HB), 256, 256, 256, 0,
        (const u16*)(ws+O_HB), ln2_g + l*256, ln2_b + l*256);
  }

  // GRU input projection -> giZ (OM=1)
  gemm_bt<4,1><<<dim3(6,338), 256, 0, stream>>>((const u16*)(ws+O_HB), 1024, (const u16*)(ws+O_WIHW),
      g_bih, nullptr, (u16*)(ws+O_GIZ), 1536, 1536, 256, 0, nullptr, nullptr, nullptr);
  gru_kernel<<<128, 128, 0, stream>>>((const u16*)(ws+O_GIZ), g_whh, g_bhh,
      (u16*)(ws+O_HX), (u16*)(ws+O_HS), (unsigned*)(ws+O_BAR));

  // head (rows m = t*128+b)
  gemm_bt<4,0><<<dim3(2,338), 256, 0, stream>>>((const u16*)(ws+O_HS), 512, (const u16*)(ws+O_FC1W),
      fc1_b, nullptr, (u16*)(ws+O_Y1), 512, 512, 512, 0, nullptr, nullptr, nullptr);
  ln_kernel<8><<<5408, 256, 0, stream>>>((const u16*)(ws+O_Y1), nullptr, fln_g, fln_b,
      (u16*)(ws+O_YB), 1);
  gemm_bt<1,3><<<dim3(1,338), 256, 0, stream>>>((const u16*)(ws+O_YB), 512, (const u16*)(ws+O_FC2W),
      (const float*)(ws+O_FC2B), (float*)d_out, nullptr, 64, 64, 512, 0, nullptr, nullptr, nullptr);
}